// Round 6
// baseline (1311.111 us; speedup 1.0000x reference)
//
#include <hip/hip_runtime.h>

#define NODES   131072
#define EDGES   2097152
#define H       128
#define NB      32        // graphs
#define PP      4096      // nodes per graph

typedef short bf16x8 __attribute__((ext_vector_type(8)));
typedef float f32x4  __attribute__((ext_vector_type(4)));
typedef unsigned short u16;

// ============================================================================
// CSR build: histogram -> hierarchical exclusive scan -> XCD-local fill
// ============================================================================
__global__ __launch_bounds__(256) void gnn_hist(const int* __restrict__ dst, int* __restrict__ counts) {
  int e = blockIdx.x * 256 + threadIdx.x;
  if (e < EDGES) atomicAdd(&counts[dst[e]], 1);
}

__global__ __launch_bounds__(256) void gnn_scan1(const int* __restrict__ counts,
                                                 int* __restrict__ rowptr, int* __restrict__ bsum) {
  __shared__ int s[256];
  int t = threadIdx.x;
  int i = blockIdx.x * 256 + t;
  int v = counts[i];
  s[t] = v; __syncthreads();
  for (int off = 1; off < 256; off <<= 1) {
    int u = (t >= off) ? s[t - off] : 0;
    __syncthreads();
    s[t] += u;
    __syncthreads();
  }
  rowptr[i] = s[t] - v;            // block-local exclusive
  if (t == 255) bsum[blockIdx.x] = s[255];
}

__global__ __launch_bounds__(512) void gnn_scan2(const int* __restrict__ bsum, int* __restrict__ boff) {
  __shared__ int s[512];
  int t = threadIdx.x;
  int v = bsum[t];
  s[t] = v; __syncthreads();
  for (int off = 1; off < 512; off <<= 1) {
    int u = (t >= off) ? s[t - off] : 0;
    __syncthreads();
    s[t] += u;
    __syncthreads();
  }
  boff[t] = s[t] - v;              // exclusive block offsets
}

// also materializes the fill cursor (overwrites counts; hist is done by now)
__global__ __launch_bounds__(256) void gnn_scan3(int* __restrict__ rowptr, const int* __restrict__ boff,
                                                 int* __restrict__ cursor) {
  int i = blockIdx.x * 256 + threadIdx.x;
  int v = rowptr[i] + boff[blockIdx.x];
  rowptr[i] = v;
  cursor[i] = v;
  if (i == 0) rowptr[NODES] = EDGES;
}

// XCD-local bucket-fill. Partition p owns dst in [p*16384,(p+1)*16384) -> a
// ~1MB epack slice. Round-5 counters proved cross-XCD partial-sector writes
// cause 8x write amplification (135MB for a 8MB target). Here a block reads
// its REAL XCD id (s_getreg HW_REG_XCC_ID, HW-verified) and claims chunks
// from that partition's ticket pool, so each slice is written by exactly one
// XCD's L2 (1MB dirty set, fits 4MB L2). Ticket pools make coverage
// scheduler-independent: every (partition,chunk) ticket is claimed exactly
// once; blocks spill to neighbor pools only when their own pool is empty.
// Input streams are nontemporal so they don't evict dirty epack lines.
// Record: src(17b)<<15 | round(ew*32768) (15b fixed point, err<=1.6e-5).
#define FILL_CHUNKS 256
#define HWREG_XCC_ID (20 | ((32 - 1) << 11))
__global__ __launch_bounds__(256) void gnn_fill(const int* __restrict__ src, const int* __restrict__ dst,
                                                const float* __restrict__ ew, int* __restrict__ cursor,
                                                int* __restrict__ tickets,
                                                unsigned* __restrict__ epack) {
  __shared__ int s_t;
  const int xcd = (int)(__builtin_amdgcn_s_getreg(HWREG_XCC_ID) & 7u);
  for (int po = 0; po < 8; ++po) {
    int part = (xcd + po) & 7;
    while (true) {
      __syncthreads();
      if (threadIdx.x == 0) s_t = atomicAdd(&tickets[part], 1);
      __syncthreads();
      int chunk = s_t;
      if (chunk >= FILL_CHUNKS) break;
      const int base = chunk * (EDGES / FILL_CHUNKS);
#pragma unroll 4
      for (int i = 0; i < (EDGES / FILL_CHUNKS) / 256; ++i) {
        int e = base + i * 256 + threadIdx.x;
        int d = __builtin_nontemporal_load(dst + e);
        int s = __builtin_nontemporal_load(src + e);
        float w = __builtin_nontemporal_load(ew + e);
        if ((d >> 14) == part) {
          int wq = (int)fminf(w * 32768.f + 0.5f, 32767.f);
          int p = atomicAdd(&cursor[d], 1);
          epack[p] = ((unsigned)s << 15) | (unsigned)wq;
        }
      }
    }
  }
}

// ============================================================================
// bf16 helpers
// ============================================================================
__device__ __forceinline__ unsigned gnn_pack2bf(float a, float b) {
  union { float f; unsigned u; } x, y; x.f = a; y.f = b;
  unsigned ua = (x.u + 0x7FFFu + ((x.u >> 16) & 1u)) >> 16;
  unsigned ub = (y.u + 0x7FFFu + ((y.u >> 16) & 1u)) >> 16;
  return ua | (ub << 16);
}

__device__ __forceinline__ u16 gnn_f2bf(float a) {
  union { float f; unsigned u; } x; x.f = a;
  return (u16)((x.u + 0x7FFFu + ((x.u >> 16) & 1u)) >> 16);
}

__device__ __forceinline__ float gnn_bf2f(u16 h) {
  union { unsigned u; float f; } x; x.u = ((unsigned)h) << 16; return x.f;
}

__device__ __forceinline__ float gnn_sig(float x)  { return 1.f / (1.f + __expf(-x)); }
__device__ __forceinline__ float gnn_tanh(float x) { return 1.f - 2.f / (1.f + __expf(2.f * x)); }

// ============================================================================
// t[i,:] = sum_{e in CSR[i]} ew_e * x[src_e,:]   (one wave per node, bf16 x)
// lane covers cols {2*lane, 2*lane+1}; one 256B coalesced row read per edge.
// 16-deep software pipeline.
// ============================================================================
__device__ __forceinline__ void gnn_agg_edge(const u16* __restrict__ X, unsigned q, int lane,
                                             float& a0, float& a1) {
  unsigned pv = *(const unsigned*)(X + (long)(q >> 15) * H + lane * 2);
  float w = (float)(q & 0x7FFFu) * (1.f / 32768.f);
  union { unsigned u; float f; } lo, hi;
  lo.u = pv << 16; hi.u = pv & 0xFFFF0000u;
  a0 = fmaf(w, lo.f, a0);
  a1 = fmaf(w, hi.f, a1);
}

__global__ __launch_bounds__(256) void gnn_agg(const u16* __restrict__ X, const int* __restrict__ rowptr,
                                               const unsigned* __restrict__ epack,
                                               u16* __restrict__ T) {
  int wave = threadIdx.x >> 6, lane = threadIdx.x & 63;
  long node = (long)blockIdx.x * 4 + wave;
  int e0 = rowptr[node], e1 = rowptr[node + 1];
  float a0 = 0.f, a1 = 0.f;
  int e = e0;
  for (; e + 16 <= e1; e += 16) {
    unsigned q[16];
#pragma unroll
    for (int j = 0; j < 16; ++j) q[j] = epack[e + j];
    unsigned p[16];
#pragma unroll
    for (int j = 0; j < 16; ++j) p[j] = *(const unsigned*)(X + (long)(q[j] >> 15) * H + lane * 2);
#pragma unroll
    for (int j = 0; j < 16; ++j) {
      float w = (float)(q[j] & 0x7FFFu) * (1.f / 32768.f);
      union { unsigned u; float f; } lo, hi;
      lo.u = p[j] << 16; hi.u = p[j] & 0xFFFF0000u;
      a0 = fmaf(w, lo.f, a0);
      a1 = fmaf(w, hi.f, a1);
    }
  }
  if (e + 8 <= e1) {
    unsigned q[8];
#pragma unroll
    for (int j = 0; j < 8; ++j) q[j] = epack[e + j];
    unsigned p[8];
#pragma unroll
    for (int j = 0; j < 8; ++j) p[j] = *(const unsigned*)(X + (long)(q[j] >> 15) * H + lane * 2);
#pragma unroll
    for (int j = 0; j < 8; ++j) {
      float w = (float)(q[j] & 0x7FFFu) * (1.f / 32768.f);
      union { unsigned u; float f; } lo, hi;
      lo.u = p[j] << 16; hi.u = p[j] & 0xFFFF0000u;
      a0 = fmaf(w, lo.f, a0);
      a1 = fmaf(w, hi.f, a1);
    }
    e += 8;
  }
  if (e + 4 <= e1) {
    unsigned q[4];
#pragma unroll
    for (int j = 0; j < 4; ++j) q[j] = epack[e + j];
#pragma unroll
    for (int j = 0; j < 4; ++j) gnn_agg_edge(X, q[j], lane, a0, a1);
    e += 4;
  }
  for (; e < e1; ++e) gnn_agg_edge(X, epack[e], lane, a0, a1);
  *(unsigned*)(T + node * H + lane * 2) = gnn_pack2bf(a0, a1);
}

// ============================================================================
// weight prep: Wc = W[l] @ wi.T  (128x384), whT = wh.T (128x384)
// ============================================================================
__global__ __launch_bounds__(384) void gnn_prep_wc(const float* __restrict__ Wl, const float* __restrict__ wi,
                                                   float* __restrict__ Wc) {
  __shared__ float wrow[128];
  int k = blockIdx.x, j = threadIdx.x;
  if (j < 128) wrow[j] = Wl[k * 128 + j];
  __syncthreads();
  float acc = 0.f;
  for (int m = 0; m < 128; ++m) acc = fmaf(wrow[m], wi[j * 128 + m], acc);
  Wc[k * 384 + j] = acc;
}

__global__ __launch_bounds__(384) void gnn_prep_whT(const float* __restrict__ wh1, const float* __restrict__ wh2,
                                                    float* __restrict__ whT) {
  int c = blockIdx.x >> 7, k = blockIdx.x & 127, j = threadIdx.x;
  const float* wh = c ? wh2 : wh1;
  whT[((long)c * 128 + k) * 384 + j] = wh[j * 128 + k];
}

// ============================================================================
// MFMA fragment plumbing
// A-frag layout (16x16x32): A[m=lane&15][k=(lane>>4)*8+j]
// B-frag layout:            B[k=(lane>>4)*8+j][n=lane&15]
// C/D layout:               col=lane&15, row=(lane>>4)*4+reg
// LDS A staging: slot(ktq,row) = ktq*64 + (row ^ (ktq&7)), 16B per slot
// ============================================================================
template<int K>
__device__ __forceinline__ void gnn_stage_bf(const u16* __restrict__ A, long row0,
                                             u16* lds, int tid) {
  constexpr int CH = K / 8;     // 16B chunks per row
#pragma unroll
  for (int it = 0; it < (64 * CH) / 256; ++it) {
    int c = it * 256 + tid;
    int row = c / CH, ktq = c % CH;
    uint4 v = *(const uint4*)(A + (row0 + row) * K + ktq * 8);
    int slot = ktq * 64 + (row ^ (ktq & 7));
    *(uint4*)(lds + slot * 8) = v;
  }
}

__device__ __forceinline__ bf16x8 gnn_afrag(const u16* lds, int rt, int ktq, int l16) {
  int slot = ktq * 64 + ((rt * 16 + l16) ^ (ktq & 7));
  return *(const bf16x8*)(lds + slot * 8);
}

__device__ __forceinline__ bf16x8 gnn_bfrag(const u16* __restrict__ pk,
                                            int ct, int kt, int KT, int lane) {
  return *(const bf16x8*)(pk + (((long)(ct * KT + kt)) * 64 + lane) * 8);
}

// pack fp32 weight into B-fragment bf16 layout: dst frag (ct,kt) at [(ct*KT+kt)*64+lane]*8 halves
// source element: k<ksplit ? W0[k*LD + coff + col] : W1[(k-ksplit)*LD + coff + col]
__global__ __launch_bounds__(64) void gnn_pack(const float* __restrict__ W0, const float* __restrict__ W1,
                                               int ksplit, int LD, int coff, int KT,
                                               u16* __restrict__ dst) {
  int b = blockIdx.x;
  int kt = b % KT, ct = b / KT;
  int lane = threadIdx.x;
  int col = ct * 16 + (lane & 15) + coff;
  int kb = kt * 32 + ((lane >> 4) & 3) * 8;
  u16 h[8];
#pragma unroll
  for (int j = 0; j < 8; ++j) {
    int k = kb + j;
    float v = (k < ksplit) ? W0[(long)k * LD + col] : W1[(long)(k - ksplit) * LD + col];
    h[j] = gnn_f2bf(v);
  }
  uint4 o;
  o.x = (unsigned)h[0] | ((unsigned)h[1] << 16);
  o.y = (unsigned)h[2] | ((unsigned)h[3] << 16);
  o.z = (unsigned)h[4] | ((unsigned)h[5] << 16);
  o.w = (unsigned)h[6] | ((unsigned)h[7] << 16);
  ((uint4*)dst)[(long)b * 64 + lane] = o;
}

// ============================================================================
// MFMA GEMM: C[M x N] = act(A[M x K] @ Wpk + bias), 64-row blocks, 256 thr.
// A bf16, C bf16. wave w covers cols [w*N/4,...). BMODE 0: bias[j]; 1: per-graph
// ============================================================================
template<int K, int N, int ACT, int BMODE>
__global__ __launch_bounds__(256) void gnn_mgemm(const u16* __restrict__ A,
                                                 const u16* __restrict__ pk,
                                                 const float* __restrict__ bias,
                                                 u16* __restrict__ C) {
  constexpr int KT = K / 32;
  constexpr int CT = N / 64;       // col-tiles per wave
  __shared__ u16 As[64 * K];
  const int tid = threadIdx.x;
  const int lane = tid & 63, wave = tid >> 6;
  const int quad = lane >> 4, l16 = lane & 15;
  const long row0 = (long)blockIdx.x * 64;
  gnn_stage_bf<K>(A, row0, As, tid);
  __syncthreads();

  f32x4 zero4 = {0.f, 0.f, 0.f, 0.f};
  f32x4 acc[4][CT];
#pragma unroll
  for (int rt = 0; rt < 4; ++rt)
#pragma unroll
    for (int ct = 0; ct < CT; ++ct) acc[rt][ct] = zero4;

#pragma unroll
  for (int kt = 0; kt < KT; ++kt) {
    int ktq = kt * 4 + quad;
    bf16x8 af[4];
#pragma unroll
    for (int rt = 0; rt < 4; ++rt) af[rt] = gnn_afrag(As, rt, ktq, l16);
#pragma unroll
    for (int ct = 0; ct < CT; ++ct) {
      bf16x8 bf = gnn_bfrag(pk, wave * CT + ct, kt, KT, lane);
#pragma unroll
      for (int rt = 0; rt < 4; ++rt)
        acc[rt][ct] = __builtin_amdgcn_mfma_f32_16x16x32_bf16(af[rt], bf, acc[rt][ct], 0, 0, 0);
    }
  }

  const float* bp = (BMODE == 0) ? bias : (bias + (row0 >> 12) * N);
#pragma unroll
  for (int ct = 0; ct < CT; ++ct) {
    int col = (wave * CT + ct) * 16 + l16;
    float bv = bp[col];
#pragma unroll
    for (int rt = 0; rt < 4; ++rt) {
      long row = row0 + rt * 16 + quad * 4;
#pragma unroll
      for (int r = 0; r < 4; ++r) {
        float v = acc[rt][ct][r] + bv;
        if (ACT) v = fmaxf(v, 0.f);
        C[(row + r) * N + col] = gnn_f2bf(v);
      }
    }
  }
}

// ============================================================================
// MFMA GRU: Y = GRUCell(m = T@Wc, h = X), all node tensors bf16.
// 64-row blocks, 256 threads; wave w covers gate cols [w*32, w*32+32).
// pkRZ: [256k x 256col] (r cols 0..127, z 128..255); pkAI/pkAH: [128 x 128]
// ============================================================================
template<int RELU>
__global__ __launch_bounds__(256) void gnn_mgru(const u16* __restrict__ T, const u16* __restrict__ X,
                                                const u16* __restrict__ pkRZ,
                                                const u16* __restrict__ pkAI,
                                                const u16* __restrict__ pkAH,
                                                const float* __restrict__ bi, const float* __restrict__ bh,
                                                u16* __restrict__ Y) {
  __shared__ u16 Ts[64 * 128];
  __shared__ u16 Xs[64 * 128];
  const int tid = threadIdx.x;
  const int lane = tid & 63, wave = tid >> 6;
  const int quad = lane >> 4, l16 = lane & 15;
  const long row0 = (long)blockIdx.x * 64;
  gnn_stage_bf<128>(T, row0, Ts, tid);
  gnn_stage_bf<128>(X, row0, Xs, tid);
  __syncthreads();

  f32x4 zero4 = {0.f, 0.f, 0.f, 0.f};
  f32x4 ai[4][2], ah[4][2], rr[4][2];
#pragma unroll
  for (int rt = 0; rt < 4; ++rt)
#pragma unroll
    for (int c = 0; c < 2; ++c) { ai[rt][c] = zero4; ah[rt][c] = zero4; rr[rt][c] = zero4; }

  // fused K-loop: ai (T), ah (X), r (T,X)
#pragma unroll
  for (int kt = 0; kt < 4; ++kt) {
    int ktq = kt * 4 + quad;
    bf16x8 tf[4], xf[4];
#pragma unroll
    for (int rt = 0; rt < 4; ++rt) { tf[rt] = gnn_afrag(Ts, rt, ktq, l16); xf[rt] = gnn_afrag(Xs, rt, ktq, l16); }
#pragma unroll
    for (int c = 0; c < 2; ++c) {
      int ct = wave * 2 + c;
      bf16x8 bAI = gnn_bfrag(pkAI, ct, kt, 4, lane);
      bf16x8 bAH = gnn_bfrag(pkAH, ct, kt, 4, lane);
      bf16x8 bRT = gnn_bfrag(pkRZ, ct, kt,     8, lane);
      bf16x8 bRX = gnn_bfrag(pkRZ, ct, kt + 4, 8, lane);
#pragma unroll
      for (int rt = 0; rt < 4; ++rt) {
        ai[rt][c] = __builtin_amdgcn_mfma_f32_16x16x32_bf16(tf[rt], bAI, ai[rt][c], 0, 0, 0);
        ah[rt][c] = __builtin_amdgcn_mfma_f32_16x16x32_bf16(xf[rt], bAH, ah[rt][c], 0, 0, 0);
        rr[rt][c] = __builtin_amdgcn_mfma_f32_16x16x32_bf16(tf[rt], bRT, rr[rt][c], 0, 0, 0);
        rr[rt][c] = __builtin_amdgcn_mfma_f32_16x16x32_bf16(xf[rt], bRX, rr[rt][c], 0, 0, 0);
      }
    }
  }

  // biases for this lane's two gate columns
  float brz[2], bzz[2], bin_[2], bhn[2];
#pragma unroll
  for (int c = 0; c < 2; ++c) {
    int col = (wave * 2 + c) * 16 + l16;
    brz[c]  = bi[col] + bh[col];
    bzz[c]  = bi[128 + col] + bh[128 + col];
    bin_[c] = bi[256 + col];
    bhn[c]  = bh[256 + col];
  }

  // n = tanh(ai + bi_n + r*(ah + bh_n))   (n overwrites ai)
#pragma unroll
  for (int rt = 0; rt < 4; ++rt)
#pragma unroll
    for (int c = 0; c < 2; ++c)
#pragma unroll
      for (int r = 0; r < 4; ++r) {
        float rv = gnn_sig(rr[rt][c][r] + brz[c]);
        ai[rt][c][r] = gnn_tanh(ai[rt][c][r] + bin_[c] + rv * (ah[rt][c][r] + bhn[c]));
      }

  // z gate
  f32x4 zz[4][2];
#pragma unroll
  for (int rt = 0; rt < 4; ++rt)
#pragma unroll
    for (int c = 0; c < 2; ++c) zz[rt][c] = zero4;
#pragma unroll
  for (int kt = 0; kt < 4; ++kt) {
    int ktq = kt * 4 + quad;
    bf16x8 tf[4], xf[4];
#pragma unroll
    for (int rt = 0; rt < 4; ++rt) { tf[rt] = gnn_afrag(Ts, rt, ktq, l16); xf[rt] = gnn_afrag(Xs, rt, ktq, l16); }
#pragma unroll
    for (int c = 0; c < 2; ++c) {
      int ct = wave * 2 + c;
      bf16x8 bZT = gnn_bfrag(pkRZ, 8 + ct, kt,     8, lane);
      bf16x8 bZX = gnn_bfrag(pkRZ, 8 + ct, kt + 4, 8, lane);
#pragma unroll
      for (int rt = 0; rt < 4; ++rt) {
        zz[rt][c] = __builtin_amdgcn_mfma_f32_16x16x32_bf16(tf[rt], bZT, zz[rt][c], 0, 0, 0);
        zz[rt][c] = __builtin_amdgcn_mfma_f32_16x16x32_bf16(xf[rt], bZX, zz[rt][c], 0, 0, 0);
      }
    }
  }

  // combine + store (h read bf16 from global X)
#pragma unroll
  for (int rt = 0; rt < 4; ++rt)
#pragma unroll
    for (int c = 0; c < 2; ++c) {
      int col = (wave * 2 + c) * 16 + l16;
      long rowb = row0 + rt * 16 + quad * 4;
#pragma unroll
      for (int r = 0; r < 4; ++r) {
        float z = gnn_sig(zz[rt][c][r] + bzz[c]);
        float h = gnn_bf2f(X[(rowb + r) * H + col]);
        float v = (1.f - z) * ai[rt][c][r] + z * h;
        if (RELU) v = fmaxf(v, 0.f);
        Y[(rowb + r) * H + col] = gnn_f2bf(v);
      }
    }
}

// ============================================================================
// fp32-input GEMM (emb1, K=16 only), bf16 output
// ============================================================================
#define GFMA(i, av) \
  acc[(i)*4+0] = fmaf((av), wv.x, acc[(i)*4+0]); \
  acc[(i)*4+1] = fmaf((av), wv.y, acc[(i)*4+1]); \
  acc[(i)*4+2] = fmaf((av), wv.z, acc[(i)*4+2]); \
  acc[(i)*4+3] = fmaf((av), wv.w, acc[(i)*4+3]);

__global__ __launch_bounds__(256) void gnn_gemm16(const float* __restrict__ A, const float* __restrict__ W,
                                                  const float* __restrict__ bias, u16* __restrict__ C,
                                                  int OUT) {
  const int K = 16;
  __shared__ float AsT[16][68];   // [k][row]
  __shared__ float Ws[16][68];    // [k][col]
  const int tid = threadIdx.x;
  const int tx = tid & 15, ty = tid >> 4;
  const long row0 = (long)blockIdx.y * 64;
  const int col0 = blockIdx.x * 64;
  const int lr  = tid >> 2;
  const int lk4 = (tid & 3) * 4;
  const int wk  = tid >> 4;
  const int wj4 = (tid & 15) * 4;
  float acc[16];
#pragma unroll
  for (int i = 0; i < 16; ++i) acc[i] = 0.f;

  {
    float4 a = *(const float4*)(A + (row0 + lr) * K + lk4);
    float4 w = *(const float4*)(W + (long)wk * OUT + col0 + wj4);
    AsT[lk4 + 0][lr] = a.x; AsT[lk4 + 1][lr] = a.y; AsT[lk4 + 2][lr] = a.z; AsT[lk4 + 3][lr] = a.w;
    *(float4*)(&Ws[wk][wj4]) = w;
    __syncthreads();
#pragma unroll
    for (int k = 0; k < 16; ++k) {
      float4 av = *(const float4*)(&AsT[k][ty * 4]);
      float4 wv = *(const float4*)(&Ws[k][tx * 4]);
      GFMA(0, av.x) GFMA(1, av.y) GFMA(2, av.z) GFMA(3, av.w)
    }
  }
#pragma unroll
  for (int i = 0; i < 4; ++i) {
    long row = row0 + ty * 4 + i;
    int j = col0 + tx * 4;
    float4 o;
    o.x = fmaxf(acc[i * 4 + 0] + bias[j + 0], 0.f);
    o.y = fmaxf(acc[i * 4 + 1] + bias[j + 1], 0.f);
    o.z = fmaxf(acc[i * 4 + 2] + bias[j + 2], 0.f);
    o.w = fmaxf(acc[i * 4 + 3] + bias[j + 3], 0.f);
    uint2 st;
    st.x = gnn_pack2bf(o.x, o.y);
    st.y = gnn_pack2bf(o.z, o.w);
    *(uint2*)(C + row * OUT + j) = st;
  }
}
#undef GFMA

// ============================================================================
// head: pool, per-graph bias, item-value init, final bound reduction
// ============================================================================
__global__ __launch_bounds__(128) void gnn_pool(const u16* __restrict__ X3, float* __restrict__ ge) {
  int b = blockIdx.x >> 3, chunk = blockIdx.x & 7, t = threadIdx.x;
  long base = ((long)b * PP + chunk * 512) * H;
  float acc = 0.f;
  for (int p = 0; p < 512; ++p) acc += gnn_bf2f(X3[base + (long)p * H + t]);
  atomicAdd(&ge[b * H + t], acc);
}

__global__ __launch_bounds__(256) void gnn_gbias(const float* __restrict__ ge, const float* __restrict__ Wl1b,
                                                 const float* __restrict__ bl1, float* __restrict__ gb) {
  __shared__ float g[128];
  int b = blockIdx.x, t = threadIdx.x;
  if (t < 128) g[t] = ge[b * H + t] * (1.f / 4096.f);
  __syncthreads();
  float acc = bl1[t];
  for (int k = 0; k < 128; ++k) acc = fmaf(g[k], Wl1b[k * 256 + t], acc);
  gb[b * 256 + t] = acc;
}

__global__ __launch_bounds__(256) void gnn_item(const float* __restrict__ iv, const int* __restrict__ vvs,
                                                float* __restrict__ out) {
  __shared__ float s[256];
  int b = blockIdx.x, t = threadIdx.x;
  float v = iv[b * 256 + t] * (float)vvs[(long)b * PP + t];   // sol[b,0,n]
  s[t] = v; __syncthreads();
  for (int off = 128; off > 0; off >>= 1) {
    if (t < off) s[t] += s[t + off];
    __syncthreads();
  }
  if (t == 0) out[b] = s[0];
}

__global__ __launch_bounds__(256) void gnn_bound(const u16* __restrict__ U2, const float* __restrict__ wl3,
                                                 const float* __restrict__ bl3, const int* __restrict__ vvs,
                                                 float* __restrict__ out) {
  int tid = threadIdx.x;
  int wave = tid >> 6, lane = tid & 63;
  int b = blockIdx.x >> 6;
  long node0 = (long)blockIdx.x * 64 + wave * 16;
  float w0 = wl3[lane * 2], w1 = wl3[lane * 2 + 1];
  float bl = bl3[0];
  float acc = 0.f;
  for (int i = 0; i < 16; ++i) {
    long node = node0 + i;
    unsigned pv = *(const unsigned*)(U2 + node * H + lane * 2);
    union { unsigned u; float f; } lo, hi;
    lo.u = pv << 16; hi.u = pv & 0xFFFF0000u;
    float p = lo.f * w0 + hi.f * w1;
#pragma unroll
    for (int off = 32; off > 0; off >>= 1) p += __shfl_down(p, off);
    if (lane == 0) {
      int pp = (int)(node & (PP - 1));
      int m = pp >> 8, n = pp & 255;
      if (m != 0) {
        float dx = (float)(vvs[((long)b << 12) + n] - vvs[((long)b << 12) + pp]);
        acc += (p + bl) * dx;
      }
    }
  }
  __shared__ float s[4];
  if (lane == 0) s[wave] = acc;
  __syncthreads();
  if (tid == 0) atomicAdd(&out[b], s[0] + s[1] + s[2] + s[3]);
}

// ============================================================================
extern "C" void kernel_launch(void* const* d_in, const int* in_sizes, int n_in,
                              void* d_out, int out_size, void* d_ws, size_t ws_size,
                              hipStream_t stream) {
  const float* G      = (const float*)d_in[0];
  const int*   ei     = (const int*)d_in[1];
  const int*   esrc   = ei;
  const int*   edst   = ei + EDGES;
  const float* ew     = (const float*)d_in[2];
  const int*   vvs    = (const int*)d_in[4];
  const float* iv     = (const float*)d_in[5];
  const float* W_emb1 = (const float*)d_in[6];
  const float* b_emb1 = (const float*)d_in[7];
  const float* W_emb2 = (const float*)d_in[8];
  const float* b_emb2 = (const float*)d_in[9];
  const float* c1_W   = (const float*)d_in[10];
  const float* c1_wi  = (const float*)d_in[11];
  const float* c1_wh  = (const float*)d_in[12];
  const float* c1_bi  = (const float*)d_in[13];
  const float* c1_bh  = (const float*)d_in[14];
  const float* c2_W   = (const float*)d_in[15];
  const float* c2_wi  = (const float*)d_in[16];
  const float* c2_wh  = (const float*)d_in[17];
  const float* c2_bi  = (const float*)d_in[18];
  const float* c2_bh  = (const float*)d_in[19];
  const float* W_g1   = (const float*)d_in[20];
  const float* b_g1   = (const float*)d_in[21];
  const float* W_g2   = (const float*)d_in[22];
  const float* b_g2   = (const float*)d_in[23];
  const float* W_l1   = (const float*)d_in[24];
  const float* b_l1   = (const float*)d_in[25];
  const float* W_l2   = (const float*)d_in[26];
  const float* b_l2   = (const float*)d_in[27];
  const float* W_l3   = (const float*)d_in[28];
  const float* b_l3   = (const float*)d_in[29];
  float* out = (float*)d_out;
  (void)in_sizes; (void)n_in; (void)out_size; (void)ws_size;

  // ---- workspace carve (~178 MiB) ----
  char* wsb = (char*)d_ws;
  size_t off = 0;
  auto carve = [&](size_t bytes) -> char* {
    char* p = wsb + off;
    off += (bytes + 255) & ~(size_t)255;
    return p;
  };
  u16*   xa     = (u16*)carve(sizeof(u16) * (size_t)NODES * H);
  u16*   xc     = (u16*)carve(sizeof(u16) * (size_t)NODES * H);
  u16*   tb     = (u16*)carve(sizeof(u16) * (size_t)NODES * H);
  u16*   u1b    = (u16*)carve(sizeof(u16) * (size_t)NODES * 256);
  float* Wc     = (float*)carve(sizeof(float) * 4 * H * 384);
  float* whT    = (float*)carve(sizeof(float) * 2 * H * 384);
  u16*   pk     = (u16*)carve(sizeof(u16) * 507904);
  int*   rowptr = (int*)carve(sizeof(int) * (NODES + 1));
  int*   cnt    = (int*)carve(sizeof(int) * NODES);      // counts, later cursor
  int*   bsum   = (int*)carve(sizeof(int) * 512);
  int*   boff   = (int*)carve(sizeof(int) * 512);
  int*   tix    = (int*)carve(sizeof(int) * 16);         // fill ticket pools
  unsigned* epack = (unsigned*)carve(sizeof(unsigned) * EDGES);
  float* ge     = (float*)carve(sizeof(float) * NB * H);
  float* gb     = (float*)carve(sizeof(float) * NB * 256);

  // packed-weight offsets (halves)
  const long RZ = 65536, AI = 16384, AH = 16384, LYR = RZ + AI + AH;  // 98304/layer
  u16* pkRZ[4]; u16* pkAI[4]; u16* pkAH[4];
  for (int l = 0; l < 4; ++l) {
    pkRZ[l] = pk + l * LYR;
    pkAI[l] = pk + l * LYR + RZ;
    pkAH[l] = pk + l * LYR + RZ + AI;
  }
  u16* pe2 = pk + 4 * LYR;
  u16* pg1 = pe2 + 16384;
  u16* pg2 = pg1 + 16384;
  u16* pl1 = pg2 + 16384;
  u16* pl2 = pl1 + 32768;

  // ---- CSR build ----
  hipMemsetAsync(cnt, 0, sizeof(int) * NODES, stream);
  hipMemsetAsync(tix, 0, sizeof(int) * 16, stream);
  hipMemsetAsync(ge, 0, sizeof(float) * NB * H, stream);
  gnn_hist<<<EDGES / 256, 256, 0, stream>>>(edst, cnt);
  gnn_scan1<<<512, 256, 0, stream>>>(cnt, rowptr, bsum);
  gnn_scan2<<<1, 512, 0, stream>>>(bsum, boff);
  gnn_scan3<<<512, 256, 0, stream>>>(rowptr, boff, cnt);   // cnt becomes cursor
  gnn_fill<<<2048, 256, 0, stream>>>(esrc, edst, ew, cnt, tix, epack);

  // ---- weight prep: Wc[l] = W[l] @ wi.T ; whT = wh.T ----
  gnn_prep_wc<<<128, 384, 0, stream>>>(c1_W,             c1_wi, Wc + 0 * 128 * 384);
  gnn_prep_wc<<<128, 384, 0, stream>>>(c1_W + 128 * 128, c1_wi, Wc + 1 * 128 * 384);
  gnn_prep_wc<<<128, 384, 0, stream>>>(c2_W,             c2_wi, Wc + 2 * 128 * 384);
  gnn_prep_wc<<<128, 384, 0, stream>>>(c2_W + 128 * 128, c2_wi, Wc + 3 * 128 * 384);
  gnn_prep_whT<<<256, 384, 0, stream>>>(c1_wh, c2_wh, whT);

  // ---- pack weights to MFMA B-frag bf16 ----
  for (int l = 0; l < 4; ++l) {
    const float* Wcl = Wc + (long)l * 128 * 384;
    const float* whl = whT + (long)(l >> 1) * 128 * 384;
    gnn_pack<<<16 * 8, 64, 0, stream>>>(Wcl, whl, 128, 384, 0,   8, pkRZ[l]);   // rz: K=256, N=256
    gnn_pack<<<8 * 4, 64, 0, stream>>>(Wcl, Wcl, 128, 384, 256, 4, pkAI[l]);    // ai: K=128, N=128
    gnn_pack<<<8 * 4, 64, 0, stream>>>(whl, whl, 128, 384, 256, 4, pkAH[l]);    // ah
  }
  gnn_pack<<<8 * 4, 64, 0, stream>>>(W_emb2, W_emb2, 128, 128, 0, 4, pe2);
  gnn_pack<<<8 * 4, 64, 0, stream>>>(W_g1,  W_g1,  128, 128, 0, 4, pg1);
  gnn_pack<<<8 * 4, 64, 0, stream>>>(W_g2,  W_g2,  128, 128, 0, 4, pg2);
  gnn_pack<<<16 * 4, 64, 0, stream>>>(W_l1, W_l1,  128, 256, 0, 4, pl1);        // x-part only (K=128,N=256)
  gnn_pack<<<8 * 8, 64, 0, stream>>>(W_l2,  W_l2,  256, 128, 0, 8, pl2);        // K=256,N=128

  // ---- embeddings: G -> xa -> xc ----
  gnn_gemm16<<<dim3(2, NODES / 64), 256, 0, stream>>>(G, W_emb1, b_emb1, xa, 128);
  gnn_mgemm<128, 128, 1, 0><<<NODES / 64, 256, 0, stream>>>(xa, pe2, b_emb2, xc);

  // ---- conv1 (x in xc) ----
  gnn_agg<<<NODES / 4, 256, 0, stream>>>(xc, rowptr, epack, tb);
  gnn_mgru<0><<<NODES / 64, 256, 0, stream>>>(tb, xc, pkRZ[0], pkAI[0], pkAH[0], c1_bi, c1_bh, xa);
  gnn_agg<<<NODES / 4, 256, 0, stream>>>(xa, rowptr, epack, tb);
  gnn_mgru<1><<<NODES / 64, 256, 0, stream>>>(tb, xa, pkRZ[1], pkAI[1], pkAH[1], c1_bi, c1_bh, xc);

  // ---- conv2 (x in xc) ----
  gnn_agg<<<NODES / 4, 256, 0, stream>>>(xc, rowptr, epack, tb);
  gnn_mgru<0><<<NODES / 64, 256, 0, stream>>>(tb, xc, pkRZ[2], pkAI[2], pkAH[2], c2_bi, c2_bh, xa);
  gnn_agg<<<NODES / 4, 256, 0, stream>>>(xa, rowptr, epack, tb);
  gnn_mgru<1><<<NODES / 64, 256, 0, stream>>>(tb, xa, pkRZ[3], pkAI[3], pkAH[3], c2_bi, c2_bh, xc);

  // ---- head GEMMs: xc -> xa -> tb (x3) ----
  gnn_mgemm<128, 128, 1, 0><<<NODES / 64, 256, 0, stream>>>(xc, pg1, b_g1, xa);
  gnn_mgemm<128, 128, 0, 0><<<NODES / 64, 256, 0, stream>>>(xa, pg2, b_g2, tb);

  // ---- pool + per-graph bias (folds ge @ W_l1[128:] + b_l1) ----
  gnn_pool<<<NB * 8, 128, 0, stream>>>(tb, ge);
  gnn_gbias<<<NB, 256, 0, stream>>>(ge, W_l1 + 128 * 256, b_l1, gb);

  // ---- MLP: l1 (graph-bias), l2, l3+reduction ----
  gnn_mgemm<128, 256, 1, 1><<<NODES / 64, 256, 0, stream>>>(tb, pl1, gb, u1b);
  gnn_mgemm<256, 128, 1, 0><<<NODES / 64, 256, 0, stream>>>(u1b, pl2, b_l2, xa);  // u2 in xa
  gnn_item<<<NB, 256, 0, stream>>>(iv, vvs, out);
  gnn_bound<<<NODES / 64, 256, 0, stream>>>(xa, W_l3, b_l3, vvs, out);
}

// Round 7
// 1067.132 us; speedup vs baseline: 1.2286x; 1.2286x over previous
//
#include <hip/hip_runtime.h>

#define NODES   131072
#define EDGES   2097152
#define H       128
#define NB      32        // graphs
#define PP      4096      // nodes per problem graph

typedef short bf16x8 __attribute__((ext_vector_type(8)));
typedef float f32x4  __attribute__((ext_vector_type(4)));
typedef unsigned short u16;

// ============================================================================
// CSR build: histogram -> hierarchical exclusive scan -> two-phase binning
// ============================================================================
__global__ __launch_bounds__(256) void gnn_hist(const int* __restrict__ dst, int* __restrict__ counts) {
  int e = blockIdx.x * 256 + threadIdx.x;
  if (e < EDGES) atomicAdd(&counts[dst[e]], 1);
}

__global__ __launch_bounds__(256) void gnn_scan1(const int* __restrict__ counts,
                                                 int* __restrict__ rowptr, int* __restrict__ bsum) {
  __shared__ int s[256];
  int t = threadIdx.x;
  int i = blockIdx.x * 256 + t;
  int v = counts[i];
  s[t] = v; __syncthreads();
  for (int off = 1; off < 256; off <<= 1) {
    int u = (t >= off) ? s[t - off] : 0;
    __syncthreads();
    s[t] += u;
    __syncthreads();
  }
  rowptr[i] = s[t] - v;            // block-local exclusive
  if (t == 255) bsum[blockIdx.x] = s[255];
}

__global__ __launch_bounds__(512) void gnn_scan2(const int* __restrict__ bsum, int* __restrict__ boff) {
  __shared__ int s[512];
  int t = threadIdx.x;
  int v = bsum[t];
  s[t] = v; __syncthreads();
  for (int off = 1; off < 512; off <<= 1) {
    int u = (t >= off) ? s[t - off] : 0;
    __syncthreads();
    s[t] += u;
    __syncthreads();
  }
  boff[t] = s[t] - v;              // exclusive block offsets
}

// finalize rowptr + materialize per-partition stage cursors (p = dst>>10)
__global__ __launch_bounds__(256) void gnn_scan3(int* __restrict__ rowptr, const int* __restrict__ boff,
                                                 int* __restrict__ pcur) {
  int i = blockIdx.x * 256 + threadIdx.x;
  int v = rowptr[i] + boff[blockIdx.x];
  rowptr[i] = v;
  if ((i & 1023) == 0) pcur[i >> 10] = v;
  if (i == 0) rowptr[NODES] = EDGES;
}

// ---------------------------------------------------------------------------
// Pass 1: bin edges into 128 dst-partitions (dst>>10). Round-4/5/6 counters
// proved fine-grained cross-XCD scatter costs 8x write amplification; here
// each tile reserves a CONTIGUOUS run per partition (one atomicAdd) and
// writes ~128B runs -> full sectors. Reads the edge list exactly once.
// Staged record: .x = src(17b)<<15 | round(ew*32768) (final epack word),
//                .y = dst.
// ---------------------------------------------------------------------------
#define B1_BLOCKS 256
#define B1_TILES  4            // tiles per block, 2048 edges per tile
__global__ __launch_bounds__(256) void gnn_bin1(const int* __restrict__ src, const int* __restrict__ dst,
                                                const float* __restrict__ ew, int* __restrict__ pcur,
                                                uint2* __restrict__ stage) {
  __shared__ int hist[128];
  __shared__ int pbase[128];
  const int tid = threadIdx.x;
  for (int t = 0; t < B1_TILES; ++t) {
    if (tid < 128) hist[tid] = 0;
    __syncthreads();
    const int ebase = blockIdx.x * (B1_TILES * 2048) + t * 2048;
    int parts[8], ranks[8];
    uint2 recs[8];
#pragma unroll
    for (int i = 0; i < 8; ++i) {
      int e = ebase + i * 256 + tid;
      int d = dst[e];
      int s = src[e];
      float w = ew[e];
      int wq = (int)fminf(w * 32768.f + 0.5f, 32767.f);
      parts[i] = d >> 10;
      recs[i].x = ((unsigned)s << 15) | (unsigned)wq;
      recs[i].y = (unsigned)d;
      ranks[i] = atomicAdd(&hist[parts[i]], 1);
    }
    __syncthreads();
    if (tid < 128) {
      int c = hist[tid];
      pbase[tid] = c ? atomicAdd(&pcur[tid], c) : 0;
    }
    __syncthreads();
#pragma unroll
    for (int i = 0; i < 8; ++i)
      stage[pbase[parts[i]] + ranks[i]] = recs[i];
    __syncthreads();
  }
}

// ---------------------------------------------------------------------------
// Pass 2: one block per partition. LDS cursors (exact CSR offsets) place each
// staged record; the 64KB epack slice is written by exactly one block (one
// XCD's L2 owns it) -> sectors fill before writeback, amplification ~1.
// ---------------------------------------------------------------------------
__global__ __launch_bounds__(256) void gnn_bin2(const uint2* __restrict__ stage,
                                                const int* __restrict__ rowptr,
                                                unsigned* __restrict__ epack) {
  __shared__ int cur[1024];
  const int tid = threadIdx.x;
  const int node0 = blockIdx.x << 10;
#pragma unroll
  for (int i = 0; i < 4; ++i) cur[i * 256 + tid] = rowptr[node0 + i * 256 + tid];
  __syncthreads();
  const int s0 = rowptr[node0];
  const int s1 = rowptr[node0 + 1024];
  for (int r = s0 + tid; r < s1; r += 256) {
    uint2 q = stage[r];
    int pos = atomicAdd(&cur[(int)q.y - node0], 1);
    epack[pos] = q.x;
  }
}

// ============================================================================
// bf16 helpers
// ============================================================================
__device__ __forceinline__ unsigned gnn_pack2bf(float a, float b) {
  union { float f; unsigned u; } x, y; x.f = a; y.f = b;
  unsigned ua = (x.u + 0x7FFFu + ((x.u >> 16) & 1u)) >> 16;
  unsigned ub = (y.u + 0x7FFFu + ((y.u >> 16) & 1u)) >> 16;
  return ua | (ub << 16);
}

__device__ __forceinline__ u16 gnn_f2bf(float a) {
  union { float f; unsigned u; } x; x.f = a;
  return (u16)((x.u + 0x7FFFu + ((x.u >> 16) & 1u)) >> 16);
}

__device__ __forceinline__ float gnn_bf2f(u16 h) {
  union { unsigned u; float f; } x; x.u = ((unsigned)h) << 16; return x.f;
}

__device__ __forceinline__ float gnn_sig(float x)  { return 1.f / (1.f + __expf(-x)); }
__device__ __forceinline__ float gnn_tanh(float x) { return 1.f - 2.f / (1.f + __expf(2.f * x)); }

// ============================================================================
// t[i,:] = sum_{e in CSR[i]} ew_e * x[src_e,:]   (one wave per node, bf16 x)
// lane covers cols {2*lane, 2*lane+1}; one 256B coalesced row read per edge.
// 16-deep software pipeline.
// ============================================================================
__device__ __forceinline__ void gnn_agg_edge(const u16* __restrict__ X, unsigned q, int lane,
                                             float& a0, float& a1) {
  unsigned pv = *(const unsigned*)(X + (long)(q >> 15) * H + lane * 2);
  float w = (float)(q & 0x7FFFu) * (1.f / 32768.f);
  union { unsigned u; float f; } lo, hi;
  lo.u = pv << 16; hi.u = pv & 0xFFFF0000u;
  a0 = fmaf(w, lo.f, a0);
  a1 = fmaf(w, hi.f, a1);
}

__global__ __launch_bounds__(256) void gnn_agg(const u16* __restrict__ X, const int* __restrict__ rowptr,
                                               const unsigned* __restrict__ epack,
                                               u16* __restrict__ T) {
  int wave = threadIdx.x >> 6, lane = threadIdx.x & 63;
  long node = (long)blockIdx.x * 4 + wave;
  int e0 = rowptr[node], e1 = rowptr[node + 1];
  float a0 = 0.f, a1 = 0.f;
  int e = e0;
  for (; e + 16 <= e1; e += 16) {
    unsigned q[16];
#pragma unroll
    for (int j = 0; j < 16; ++j) q[j] = epack[e + j];
    unsigned p[16];
#pragma unroll
    for (int j = 0; j < 16; ++j) p[j] = *(const unsigned*)(X + (long)(q[j] >> 15) * H + lane * 2);
#pragma unroll
    for (int j = 0; j < 16; ++j) {
      float w = (float)(q[j] & 0x7FFFu) * (1.f / 32768.f);
      union { unsigned u; float f; } lo, hi;
      lo.u = p[j] << 16; hi.u = p[j] & 0xFFFF0000u;
      a0 = fmaf(w, lo.f, a0);
      a1 = fmaf(w, hi.f, a1);
    }
  }
  if (e + 8 <= e1) {
    unsigned q[8];
#pragma unroll
    for (int j = 0; j < 8; ++j) q[j] = epack[e + j];
    unsigned p[8];
#pragma unroll
    for (int j = 0; j < 8; ++j) p[j] = *(const unsigned*)(X + (long)(q[j] >> 15) * H + lane * 2);
#pragma unroll
    for (int j = 0; j < 8; ++j) {
      float w = (float)(q[j] & 0x7FFFu) * (1.f / 32768.f);
      union { unsigned u; float f; } lo, hi;
      lo.u = p[j] << 16; hi.u = p[j] & 0xFFFF0000u;
      a0 = fmaf(w, lo.f, a0);
      a1 = fmaf(w, hi.f, a1);
    }
    e += 8;
  }
  if (e + 4 <= e1) {
    unsigned q[4];
#pragma unroll
    for (int j = 0; j < 4; ++j) q[j] = epack[e + j];
#pragma unroll
    for (int j = 0; j < 4; ++j) gnn_agg_edge(X, q[j], lane, a0, a1);
    e += 4;
  }
  for (; e < e1; ++e) gnn_agg_edge(X, epack[e], lane, a0, a1);
  *(unsigned*)(T + node * H + lane * 2) = gnn_pack2bf(a0, a1);
}

// ============================================================================
// weight prep: Wc = W[l] @ wi.T  (128x384), whT = wh.T (128x384)
// ============================================================================
__global__ __launch_bounds__(384) void gnn_prep_wc(const float* __restrict__ Wl, const float* __restrict__ wi,
                                                   float* __restrict__ Wc) {
  __shared__ float wrow[128];
  int k = blockIdx.x, j = threadIdx.x;
  if (j < 128) wrow[j] = Wl[k * 128 + j];
  __syncthreads();
  float acc = 0.f;
  for (int m = 0; m < 128; ++m) acc = fmaf(wrow[m], wi[j * 128 + m], acc);
  Wc[k * 384 + j] = acc;
}

__global__ __launch_bounds__(384) void gnn_prep_whT(const float* __restrict__ wh1, const float* __restrict__ wh2,
                                                    float* __restrict__ whT) {
  int c = blockIdx.x >> 7, k = blockIdx.x & 127, j = threadIdx.x;
  const float* wh = c ? wh2 : wh1;
  whT[((long)c * 128 + k) * 384 + j] = wh[j * 128 + k];
}

// ============================================================================
// MFMA fragment plumbing
// A-frag layout (16x16x32): A[m=lane&15][k=(lane>>4)*8+j]
// B-frag layout:            B[k=(lane>>4)*8+j][n=lane&15]
// C/D layout:               col=lane&15, row=(lane>>4)*4+reg
// LDS A staging: slot(ktq,row) = ktq*64 + (row ^ (ktq&7)), 16B per slot
// ============================================================================
template<int K>
__device__ __forceinline__ void gnn_stage_bf(const u16* __restrict__ A, long row0,
                                             u16* lds, int tid) {
  constexpr int CH = K / 8;     // 16B chunks per row
#pragma unroll
  for (int it = 0; it < (64 * CH) / 256; ++it) {
    int c = it * 256 + tid;
    int row = c / CH, ktq = c % CH;
    uint4 v = *(const uint4*)(A + (row0 + row) * K + ktq * 8);
    int slot = ktq * 64 + (row ^ (ktq & 7));
    *(uint4*)(lds + slot * 8) = v;
  }
}

__device__ __forceinline__ bf16x8 gnn_afrag(const u16* lds, int rt, int ktq, int l16) {
  int slot = ktq * 64 + ((rt * 16 + l16) ^ (ktq & 7));
  return *(const bf16x8*)(lds + slot * 8);
}

__device__ __forceinline__ bf16x8 gnn_bfrag(const u16* __restrict__ pk,
                                            int ct, int kt, int KT, int lane) {
  return *(const bf16x8*)(pk + (((long)(ct * KT + kt)) * 64 + lane) * 8);
}

// pack fp32 weight into B-fragment bf16 layout
__global__ __launch_bounds__(64) void gnn_pack(const float* __restrict__ W0, const float* __restrict__ W1,
                                               int ksplit, int LD, int coff, int KT,
                                               u16* __restrict__ dst) {
  int b = blockIdx.x;
  int kt = b % KT, ct = b / KT;
  int lane = threadIdx.x;
  int col = ct * 16 + (lane & 15) + coff;
  int kb = kt * 32 + ((lane >> 4) & 3) * 8;
  u16 h[8];
#pragma unroll
  for (int j = 0; j < 8; ++j) {
    int k = kb + j;
    float v = (k < ksplit) ? W0[(long)k * LD + col] : W1[(long)(k - ksplit) * LD + col];
    h[j] = gnn_f2bf(v);
  }
  uint4 o;
  o.x = (unsigned)h[0] | ((unsigned)h[1] << 16);
  o.y = (unsigned)h[2] | ((unsigned)h[3] << 16);
  o.z = (unsigned)h[4] | ((unsigned)h[5] << 16);
  o.w = (unsigned)h[6] | ((unsigned)h[7] << 16);
  ((uint4*)dst)[(long)b * 64 + lane] = o;
}

// ============================================================================
// MFMA GEMM: C[M x N] = act(A[M x K] @ Wpk + bias), 64-row blocks, 256 thr.
// ============================================================================
template<int K, int N, int ACT, int BMODE>
__global__ __launch_bounds__(256) void gnn_mgemm(const u16* __restrict__ A,
                                                 const u16* __restrict__ pk,
                                                 const float* __restrict__ bias,
                                                 u16* __restrict__ C) {
  constexpr int KT = K / 32;
  constexpr int CT = N / 64;       // col-tiles per wave
  __shared__ u16 As[64 * K];
  const int tid = threadIdx.x;
  const int lane = tid & 63, wave = tid >> 6;
  const int quad = lane >> 4, l16 = lane & 15;
  const long row0 = (long)blockIdx.x * 64;
  gnn_stage_bf<K>(A, row0, As, tid);
  __syncthreads();

  f32x4 zero4 = {0.f, 0.f, 0.f, 0.f};
  f32x4 acc[4][CT];
#pragma unroll
  for (int rt = 0; rt < 4; ++rt)
#pragma unroll
    for (int ct = 0; ct < CT; ++ct) acc[rt][ct] = zero4;

#pragma unroll
  for (int kt = 0; kt < KT; ++kt) {
    int ktq = kt * 4 + quad;
    bf16x8 af[4];
#pragma unroll
    for (int rt = 0; rt < 4; ++rt) af[rt] = gnn_afrag(As, rt, ktq, l16);
#pragma unroll
    for (int ct = 0; ct < CT; ++ct) {
      bf16x8 bf = gnn_bfrag(pk, wave * CT + ct, kt, KT, lane);
#pragma unroll
      for (int rt = 0; rt < 4; ++rt)
        acc[rt][ct] = __builtin_amdgcn_mfma_f32_16x16x32_bf16(af[rt], bf, acc[rt][ct], 0, 0, 0);
    }
  }

  const float* bp = (BMODE == 0) ? bias : (bias + (row0 >> 12) * N);
#pragma unroll
  for (int ct = 0; ct < CT; ++ct) {
    int col = (wave * CT + ct) * 16 + l16;
    float bv = bp[col];
#pragma unroll
    for (int rt = 0; rt < 4; ++rt) {
      long row = row0 + rt * 16 + quad * 4;
#pragma unroll
      for (int r = 0; r < 4; ++r) {
        float v = acc[rt][ct][r] + bv;
        if (ACT) v = fmaxf(v, 0.f);
        C[(row + r) * N + col] = gnn_f2bf(v);
      }
    }
  }
}

// ============================================================================
// MFMA GRU: Y = GRUCell(m = T@Wc, h = X), all node tensors bf16.
// ============================================================================
template<int RELU>
__global__ __launch_bounds__(256) void gnn_mgru(const u16* __restrict__ T, const u16* __restrict__ X,
                                                const u16* __restrict__ pkRZ,
                                                const u16* __restrict__ pkAI,
                                                const u16* __restrict__ pkAH,
                                                const float* __restrict__ bi, const float* __restrict__ bh,
                                                u16* __restrict__ Y) {
  __shared__ u16 Ts[64 * 128];
  __shared__ u16 Xs[64 * 128];
  const int tid = threadIdx.x;
  const int lane = tid & 63, wave = tid >> 6;
  const int quad = lane >> 4, l16 = lane & 15;
  const long row0 = (long)blockIdx.x * 64;
  gnn_stage_bf<128>(T, row0, Ts, tid);
  gnn_stage_bf<128>(X, row0, Xs, tid);
  __syncthreads();

  f32x4 zero4 = {0.f, 0.f, 0.f, 0.f};
  f32x4 ai[4][2], ah[4][2], rr[4][2];
#pragma unroll
  for (int rt = 0; rt < 4; ++rt)
#pragma unroll
    for (int c = 0; c < 2; ++c) { ai[rt][c] = zero4; ah[rt][c] = zero4; rr[rt][c] = zero4; }

  // fused K-loop: ai (T), ah (X), r (T,X)
#pragma unroll
  for (int kt = 0; kt < 4; ++kt) {
    int ktq = kt * 4 + quad;
    bf16x8 tf[4], xf[4];
#pragma unroll
    for (int rt = 0; rt < 4; ++rt) { tf[rt] = gnn_afrag(Ts, rt, ktq, l16); xf[rt] = gnn_afrag(Xs, rt, ktq, l16); }
#pragma unroll
    for (int c = 0; c < 2; ++c) {
      int ct = wave * 2 + c;
      bf16x8 bAI = gnn_bfrag(pkAI, ct, kt, 4, lane);
      bf16x8 bAH = gnn_bfrag(pkAH, ct, kt, 4, lane);
      bf16x8 bRT = gnn_bfrag(pkRZ, ct, kt,     8, lane);
      bf16x8 bRX = gnn_bfrag(pkRZ, ct, kt + 4, 8, lane);
#pragma unroll
      for (int rt = 0; rt < 4; ++rt) {
        ai[rt][c] = __builtin_amdgcn_mfma_f32_16x16x32_bf16(tf[rt], bAI, ai[rt][c], 0, 0, 0);
        ah[rt][c] = __builtin_amdgcn_mfma_f32_16x16x32_bf16(xf[rt], bAH, ah[rt][c], 0, 0, 0);
        rr[rt][c] = __builtin_amdgcn_mfma_f32_16x16x32_bf16(tf[rt], bRT, rr[rt][c], 0, 0, 0);
        rr[rt][c] = __builtin_amdgcn_mfma_f32_16x16x32_bf16(xf[rt], bRX, rr[rt][c], 0, 0, 0);
      }
    }
  }

  // biases for this lane's two gate columns
  float brz[2], bzz[2], bin_[2], bhn[2];
#pragma unroll
  for (int c = 0; c < 2; ++c) {
    int col = (wave * 2 + c) * 16 + l16;
    brz[c]  = bi[col] + bh[col];
    bzz[c]  = bi[128 + col] + bh[128 + col];
    bin_[c] = bi[256 + col];
    bhn[c]  = bh[256 + col];
  }

  // n = tanh(ai + bi_n + r*(ah + bh_n))   (n overwrites ai)
#pragma unroll
  for (int rt = 0; rt < 4; ++rt)
#pragma unroll
    for (int c = 0; c < 2; ++c)
#pragma unroll
      for (int r = 0; r < 4; ++r) {
        float rv = gnn_sig(rr[rt][c][r] + brz[c]);
        ai[rt][c][r] = gnn_tanh(ai[rt][c][r] + bin_[c] + rv * (ah[rt][c][r] + bhn[c]));
      }

  // z gate
  f32x4 zz[4][2];
#pragma unroll
  for (int rt = 0; rt < 4; ++rt)
#pragma unroll
    for (int c = 0; c < 2; ++c) zz[rt][c] = zero4;
#pragma unroll
  for (int kt = 0; kt < 4; ++kt) {
    int ktq = kt * 4 + quad;
    bf16x8 tf[4], xf[4];
#pragma unroll
    for (int rt = 0; rt < 4; ++rt) { tf[rt] = gnn_afrag(Ts, rt, ktq, l16); xf[rt] = gnn_afrag(Xs, rt, ktq, l16); }
#pragma unroll
    for (int c = 0; c < 2; ++c) {
      int ct = wave * 2 + c;
      bf16x8 bZT = gnn_bfrag(pkRZ, 8 + ct, kt,     8, lane);
      bf16x8 bZX = gnn_bfrag(pkRZ, 8 + ct, kt + 4, 8, lane);
#pragma unroll
      for (int rt = 0; rt < 4; ++rt) {
        zz[rt][c] = __builtin_amdgcn_mfma_f32_16x16x32_bf16(tf[rt], bZT, zz[rt][c], 0, 0, 0);
        zz[rt][c] = __builtin_amdgcn_mfma_f32_16x16x32_bf16(xf[rt], bZX, zz[rt][c], 0, 0, 0);
      }
    }
  }

  // combine + store (h read bf16 from global X)
#pragma unroll
  for (int rt = 0; rt < 4; ++rt)
#pragma unroll
    for (int c = 0; c < 2; ++c) {
      int col = (wave * 2 + c) * 16 + l16;
      long rowb = row0 + rt * 16 + quad * 4;
#pragma unroll
      for (int r = 0; r < 4; ++r) {
        float z = gnn_sig(zz[rt][c][r] + bzz[c]);
        float h = gnn_bf2f(X[(rowb + r) * H + col]);
        float v = (1.f - z) * ai[rt][c][r] + z * h;
        if (RELU) v = fmaxf(v, 0.f);
        Y[(rowb + r) * H + col] = gnn_f2bf(v);
      }
    }
}

// ============================================================================
// fp32-input GEMM (emb1, K=16 only), bf16 output
// ============================================================================
#define GFMA(i, av) \
  acc[(i)*4+0] = fmaf((av), wv.x, acc[(i)*4+0]); \
  acc[(i)*4+1] = fmaf((av), wv.y, acc[(i)*4+1]); \
  acc[(i)*4+2] = fmaf((av), wv.z, acc[(i)*4+2]); \
  acc[(i)*4+3] = fmaf((av), wv.w, acc[(i)*4+3]);

__global__ __launch_bounds__(256) void gnn_gemm16(const float* __restrict__ A, const float* __restrict__ W,
                                                  const float* __restrict__ bias, u16* __restrict__ C,
                                                  int OUT) {
  const int K = 16;
  __shared__ float AsT[16][68];   // [k][row]
  __shared__ float Ws[16][68];    // [k][col]
  const int tid = threadIdx.x;
  const int tx = tid & 15, ty = tid >> 4;
  const long row0 = (long)blockIdx.y * 64;
  const int col0 = blockIdx.x * 64;
  const int lr  = tid >> 2;
  const int lk4 = (tid & 3) * 4;
  const int wk  = tid >> 4;
  const int wj4 = (tid & 15) * 4;
  float acc[16];
#pragma unroll
  for (int i = 0; i < 16; ++i) acc[i] = 0.f;

  {
    float4 a = *(const float4*)(A + (row0 + lr) * K + lk4);
    float4 w = *(const float4*)(W + (long)wk * OUT + col0 + wj4);
    AsT[lk4 + 0][lr] = a.x; AsT[lk4 + 1][lr] = a.y; AsT[lk4 + 2][lr] = a.z; AsT[lk4 + 3][lr] = a.w;
    *(float4*)(&Ws[wk][wj4]) = w;
    __syncthreads();
#pragma unroll
    for (int k = 0; k < 16; ++k) {
      float4 av = *(const float4*)(&AsT[k][ty * 4]);
      float4 wv = *(const float4*)(&Ws[k][tx * 4]);
      GFMA(0, av.x) GFMA(1, av.y) GFMA(2, av.z) GFMA(3, av.w)
    }
  }
#pragma unroll
  for (int i = 0; i < 4; ++i) {
    long row = row0 + ty * 4 + i;
    int j = col0 + tx * 4;
    float4 o;
    o.x = fmaxf(acc[i * 4 + 0] + bias[j + 0], 0.f);
    o.y = fmaxf(acc[i * 4 + 1] + bias[j + 1], 0.f);
    o.z = fmaxf(acc[i * 4 + 2] + bias[j + 2], 0.f);
    o.w = fmaxf(acc[i * 4 + 3] + bias[j + 3], 0.f);
    uint2 st;
    st.x = gnn_pack2bf(o.x, o.y);
    st.y = gnn_pack2bf(o.z, o.w);
    *(uint2*)(C + row * OUT + j) = st;
  }
}
#undef GFMA

// ============================================================================
// head: pool, per-graph bias, item-value init, final bound reduction
// ============================================================================
__global__ __launch_bounds__(128) void gnn_pool(const u16* __restrict__ X3, float* __restrict__ ge) {
  int b = blockIdx.x >> 3, chunk = blockIdx.x & 7, t = threadIdx.x;
  long base = ((long)b * PP + chunk * 512) * H;
  float acc = 0.f;
  for (int p = 0; p < 512; ++p) acc += gnn_bf2f(X3[base + (long)p * H + t]);
  atomicAdd(&ge[b * H + t], acc);
}

__global__ __launch_bounds__(256) void gnn_gbias(const float* __restrict__ ge, const float* __restrict__ Wl1b,
                                                 const float* __restrict__ bl1, float* __restrict__ gb) {
  __shared__ float g[128];
  int b = blockIdx.x, t = threadIdx.x;
  if (t < 128) g[t] = ge[b * H + t] * (1.f / 4096.f);
  __syncthreads();
  float acc = bl1[t];
  for (int k = 0; k < 128; ++k) acc = fmaf(g[k], Wl1b[k * 256 + t], acc);
  gb[b * 256 + t] = acc;
}

__global__ __launch_bounds__(256) void gnn_item(const float* __restrict__ iv, const int* __restrict__ vvs,
                                                float* __restrict__ out) {
  __shared__ float s[256];
  int b = blockIdx.x, t = threadIdx.x;
  float v = iv[b * 256 + t] * (float)vvs[(long)b * PP + t];   // sol[b,0,n]
  s[t] = v; __syncthreads();
  for (int off = 128; off > 0; off >>= 1) {
    if (t < off) s[t] += s[t + off];
    __syncthreads();
  }
  if (t == 0) out[b] = s[0];
}

__global__ __launch_bounds__(256) void gnn_bound(const u16* __restrict__ U2, const float* __restrict__ wl3,
                                                 const float* __restrict__ bl3, const int* __restrict__ vvs,
                                                 float* __restrict__ out) {
  int tid = threadIdx.x;
  int wave = tid >> 6, lane = tid & 63;
  int b = blockIdx.x >> 6;
  long node0 = (long)blockIdx.x * 64 + wave * 16;
  float w0 = wl3[lane * 2], w1 = wl3[lane * 2 + 1];
  float bl = bl3[0];
  float acc = 0.f;
  for (int i = 0; i < 16; ++i) {
    long node = node0 + i;
    unsigned pv = *(const unsigned*)(U2 + node * H + lane * 2);
    union { unsigned u; float f; } lo, hi;
    lo.u = pv << 16; hi.u = pv & 0xFFFF0000u;
    float p = lo.f * w0 + hi.f * w1;
#pragma unroll
    for (int off = 32; off > 0; off >>= 1) p += __shfl_down(p, off);
    if (lane == 0) {
      int pp = (int)(node & (PP - 1));
      int m = pp >> 8, n = pp & 255;
      if (m != 0) {
        float dx = (float)(vvs[((long)b << 12) + n] - vvs[((long)b << 12) + pp]);
        acc += (p + bl) * dx;
      }
    }
  }
  __shared__ float s[4];
  if (lane == 0) s[wave] = acc;
  __syncthreads();
  if (tid == 0) atomicAdd(&out[b], s[0] + s[1] + s[2] + s[3]);
}

// ============================================================================
extern "C" void kernel_launch(void* const* d_in, const int* in_sizes, int n_in,
                              void* d_out, int out_size, void* d_ws, size_t ws_size,
                              hipStream_t stream) {
  const float* G      = (const float*)d_in[0];
  const int*   ei     = (const int*)d_in[1];
  const int*   esrc   = ei;
  const int*   edst   = ei + EDGES;
  const float* ew     = (const float*)d_in[2];
  const int*   vvs    = (const int*)d_in[4];
  const float* iv     = (const float*)d_in[5];
  const float* W_emb1 = (const float*)d_in[6];
  const float* b_emb1 = (const float*)d_in[7];
  const float* W_emb2 = (const float*)d_in[8];
  const float* b_emb2 = (const float*)d_in[9];
  const float* c1_W   = (const float*)d_in[10];
  const float* c1_wi  = (const float*)d_in[11];
  const float* c1_wh  = (const float*)d_in[12];
  const float* c1_bi  = (const float*)d_in[13];
  const float* c1_bh  = (const float*)d_in[14];
  const float* c2_W   = (const float*)d_in[15];
  const float* c2_wi  = (const float*)d_in[16];
  const float* c2_wh  = (const float*)d_in[17];
  const float* c2_bi  = (const float*)d_in[18];
  const float* c2_bh  = (const float*)d_in[19];
  const float* W_g1   = (const float*)d_in[20];
  const float* b_g1   = (const float*)d_in[21];
  const float* W_g2   = (const float*)d_in[22];
  const float* b_g2   = (const float*)d_in[23];
  const float* W_l1   = (const float*)d_in[24];
  const float* b_l1   = (const float*)d_in[25];
  const float* W_l2   = (const float*)d_in[26];
  const float* b_l2   = (const float*)d_in[27];
  const float* W_l3   = (const float*)d_in[28];
  const float* b_l3   = (const float*)d_in[29];
  float* out = (float*)d_out;
  (void)in_sizes; (void)n_in; (void)out_size; (void)ws_size;

  // ---- workspace carve (~194 MiB) ----
  char* wsb = (char*)d_ws;
  size_t off = 0;
  auto carve = [&](size_t bytes) -> char* {
    char* p = wsb + off;
    off += (bytes + 255) & ~(size_t)255;
    return p;
  };
  u16*   xa     = (u16*)carve(sizeof(u16) * (size_t)NODES * H);
  u16*   xc     = (u16*)carve(sizeof(u16) * (size_t)NODES * H);
  u16*   tb     = (u16*)carve(sizeof(u16) * (size_t)NODES * H);
  u16*   u1b    = (u16*)carve(sizeof(u16) * (size_t)NODES * 256);
  float* Wc     = (float*)carve(sizeof(float) * 4 * H * 384);
  float* whT    = (float*)carve(sizeof(float) * 2 * H * 384);
  u16*   pk     = (u16*)carve(sizeof(u16) * 507904);
  int*   rowptr = (int*)carve(sizeof(int) * (NODES + 1));
  int*   cnt    = (int*)carve(sizeof(int) * NODES);      // hist counts
  int*   bsum   = (int*)carve(sizeof(int) * 512);
  int*   boff   = (int*)carve(sizeof(int) * 512);
  int*   pcur   = (int*)carve(sizeof(int) * 128);        // bin1 partition cursors
  uint2* stage  = (uint2*)carve(sizeof(uint2) * EDGES);  // 16 MB staging
  unsigned* epack = (unsigned*)carve(sizeof(unsigned) * EDGES);
  float* ge     = (float*)carve(sizeof(float) * NB * H);
  float* gb     = (float*)carve(sizeof(float) * NB * 256);

  // packed-weight offsets (halves)
  const long RZ = 65536, AI = 16384, AH = 16384, LYR = RZ + AI + AH;  // 98304/layer
  u16* pkRZ[4]; u16* pkAI[4]; u16* pkAH[4];
  for (int l = 0; l < 4; ++l) {
    pkRZ[l] = pk + l * LYR;
    pkAI[l] = pk + l * LYR + RZ;
    pkAH[l] = pk + l * LYR + RZ + AI;
  }
  u16* pe2 = pk + 4 * LYR;
  u16* pg1 = pe2 + 16384;
  u16* pg2 = pg1 + 16384;
  u16* pl1 = pg2 + 16384;
  u16* pl2 = pl1 + 32768;

  // ---- CSR build: hist -> scan -> bin1 (partition stage) -> bin2 (exact) ----
  hipMemsetAsync(cnt, 0, sizeof(int) * NODES, stream);
  hipMemsetAsync(ge, 0, sizeof(float) * NB * H, stream);
  gnn_hist<<<EDGES / 256, 256, 0, stream>>>(edst, cnt);
  gnn_scan1<<<512, 256, 0, stream>>>(cnt, rowptr, bsum);
  gnn_scan2<<<1, 512, 0, stream>>>(bsum, boff);
  gnn_scan3<<<512, 256, 0, stream>>>(rowptr, boff, pcur);
  gnn_bin1<<<B1_BLOCKS, 256, 0, stream>>>(esrc, edst, ew, pcur, stage);
  gnn_bin2<<<128, 256, 0, stream>>>(stage, rowptr, epack);

  // ---- weight prep: Wc[l] = W[l] @ wi.T ; whT = wh.T ----
  gnn_prep_wc<<<128, 384, 0, stream>>>(c1_W,             c1_wi, Wc + 0 * 128 * 384);
  gnn_prep_wc<<<128, 384, 0, stream>>>(c1_W + 128 * 128, c1_wi, Wc + 1 * 128 * 384);
  gnn_prep_wc<<<128, 384, 0, stream>>>(c2_W,             c2_wi, Wc + 2 * 128 * 384);
  gnn_prep_wc<<<128, 384, 0, stream>>>(c2_W + 128 * 128, c2_wi, Wc + 3 * 128 * 384);
  gnn_prep_whT<<<256, 384, 0, stream>>>(c1_wh, c2_wh, whT);

  // ---- pack weights to MFMA B-frag bf16 ----
  for (int l = 0; l < 4; ++l) {
    const float* Wcl = Wc + (long)l * 128 * 384;
    const float* whl = whT + (long)(l >> 1) * 128 * 384;
    gnn_pack<<<16 * 8, 64, 0, stream>>>(Wcl, whl, 128, 384, 0,   8, pkRZ[l]);   // rz: K=256, N=256
    gnn_pack<<<8 * 4, 64, 0, stream>>>(Wcl, Wcl, 128, 384, 256, 4, pkAI[l]);    // ai: K=128, N=128
    gnn_pack<<<8 * 4, 64, 0, stream>>>(whl, whl, 128, 384, 256, 4, pkAH[l]);    // ah
  }
  gnn_pack<<<8 * 4, 64, 0, stream>>>(W_emb2, W_emb2, 128, 128, 0, 4, pe2);
  gnn_pack<<<8 * 4, 64, 0, stream>>>(W_g1,  W_g1,  128, 128, 0, 4, pg1);
  gnn_pack<<<8 * 4, 64, 0, stream>>>(W_g2,  W_g2,  128, 128, 0, 4, pg2);
  gnn_pack<<<16 * 4, 64, 0, stream>>>(W_l1, W_l1,  128, 256, 0, 4, pl1);        // x-part only (K=128,N=256)
  gnn_pack<<<8 * 8, 64, 0, stream>>>(W_l2,  W_l2,  256, 128, 0, 8, pl2);        // K=256,N=128

  // ---- embeddings: G -> xa -> xc ----
  gnn_gemm16<<<dim3(2, NODES / 64), 256, 0, stream>>>(G, W_emb1, b_emb1, xa, 128);
  gnn_mgemm<128, 128, 1, 0><<<NODES / 64, 256, 0, stream>>>(xa, pe2, b_emb2, xc);

  // ---- conv1 (x in xc) ----
  gnn_agg<<<NODES / 4, 256, 0, stream>>>(xc, rowptr, epack, tb);
  gnn_mgru<0><<<NODES / 64, 256, 0, stream>>>(tb, xc, pkRZ[0], pkAI[0], pkAH[0], c1_bi, c1_bh, xa);
  gnn_agg<<<NODES / 4, 256, 0, stream>>>(xa, rowptr, epack, tb);
  gnn_mgru<1><<<NODES / 64, 256, 0, stream>>>(tb, xa, pkRZ[1], pkAI[1], pkAH[1], c1_bi, c1_bh, xc);

  // ---- conv2 (x in xc) ----
  gnn_agg<<<NODES / 4, 256, 0, stream>>>(xc, rowptr, epack, tb);
  gnn_mgru<0><<<NODES / 64, 256, 0, stream>>>(tb, xc, pkRZ[2], pkAI[2], pkAH[2], c2_bi, c2_bh, xa);
  gnn_agg<<<NODES / 4, 256, 0, stream>>>(xa, rowptr, epack, tb);
  gnn_mgru<1><<<NODES / 64, 256, 0, stream>>>(tb, xa, pkRZ[3], pkAI[3], pkAH[3], c2_bi, c2_bh, xc);

  // ---- head GEMMs: xc -> xa -> tb (x3) ----
  gnn_mgemm<128, 128, 1, 0><<<NODES / 64, 256, 0, stream>>>(xc, pg1, b_g1, xa);
  gnn_mgemm<128, 128, 0, 0><<<NODES / 64, 256, 0, stream>>>(xa, pg2, b_g2, tb);

  // ---- pool + per-graph bias (folds ge @ W_l1[128:] + b_l1) ----
  gnn_pool<<<NB * 8, 128, 0, stream>>>(tb, ge);
  gnn_gbias<<<NB, 256, 0, stream>>>(ge, W_l1 + 128 * 256, b_l1, gb);

  // ---- MLP: l1 (graph-bias), l2, l3+reduction ----
  gnn_mgemm<128, 256, 1, 1><<<NODES / 64, 256, 0, stream>>>(tb, pl1, gb, u1b);
  gnn_mgemm<256, 128, 1, 0><<<NODES / 64, 256, 0, stream>>>(u1b, pl2, b_l2, xa);  // u2 in xa
  gnn_item<<<NB, 256, 0, stream>>>(iv, vvs, out);
  gnn_bound<<<NODES / 64, 256, 0, stream>>>(xa, W_l3, b_l3, vvs, out);
}

// Round 8
// 1018.355 us; speedup vs baseline: 1.2875x; 1.0479x over previous
//
#include <hip/hip_runtime.h>

#define NODES   131072
#define EDGES   2097152
#define H       128
#define NB      32        // graphs
#define PP      4096      // nodes per problem graph

typedef short bf16x8 __attribute__((ext_vector_type(8)));
typedef float f32x4  __attribute__((ext_vector_type(4)));
typedef unsigned short u16;

// ============================================================================
// CSR build, histogram-free (round-7: global-atomic hist cost 82us / 65MB of
// sector RMW writes for a 512KB array). Partition p = dst>>10 gets a fixed
// staging slab of CAPP records (mean 16384, +16 sigma slack; dst uniform).
// bin1 stages partition-binned records with contiguous-run writes; pscan
// turns partition counts into global bases; bin2 builds the rowptr slice
// from an LDS histogram + scan, then scatters into epack (one block owns
// each 64KB slice -> no cross-XCD write amplification).
// ============================================================================
#define CAPP 18432

__global__ __launch_bounds__(128) void gnn_pinit(int* __restrict__ pcur) {
  pcur[threadIdx.x] = threadIdx.x * CAPP;
}

// Staged record: .x = src(17b)<<15 | round(ew*32768) (final epack word), .y = dst
#define B1_BLOCKS 256
#define B1_TILES  4            // tiles per block, 2048 edges per tile
__global__ __launch_bounds__(256) void gnn_bin1(const int* __restrict__ src, const int* __restrict__ dst,
                                                const float* __restrict__ ew, int* __restrict__ pcur,
                                                uint2* __restrict__ stage) {
  __shared__ int hist[128];
  __shared__ int pbase[128];
  const int tid = threadIdx.x;
  for (int t = 0; t < B1_TILES; ++t) {
    if (tid < 128) hist[tid] = 0;
    __syncthreads();
    const int ebase = blockIdx.x * (B1_TILES * 2048) + t * 2048;
    int parts[8], ranks[8];
    uint2 recs[8];
#pragma unroll
    for (int i = 0; i < 8; ++i) {
      int e = ebase + i * 256 + tid;
      int d = dst[e];
      int s = src[e];
      float w = ew[e];
      int wq = (int)fminf(w * 32768.f + 0.5f, 32767.f);
      parts[i] = d >> 10;
      recs[i].x = ((unsigned)s << 15) | (unsigned)wq;
      recs[i].y = (unsigned)d;
      ranks[i] = atomicAdd(&hist[parts[i]], 1);
    }
    __syncthreads();
    if (tid < 128) {
      int c = hist[tid];
      pbase[tid] = c ? atomicAdd(&pcur[tid], c) : 0;
    }
    __syncthreads();
#pragma unroll
    for (int i = 0; i < 8; ++i)
      stage[pbase[parts[i]] + ranks[i]] = recs[i];
    __syncthreads();
  }
}

// exclusive scan of partition counts -> global epack bases
__global__ __launch_bounds__(128) void gnn_pscan(const int* __restrict__ pcur, int* __restrict__ pbase) {
  __shared__ int s[128];
  int t = threadIdx.x;
  int v = pcur[t] - t * CAPP;
  s[t] = v; __syncthreads();
  for (int o = 1; o < 128; o <<= 1) {
    int u = (t >= o) ? s[t - o] : 0;
    __syncthreads();
    s[t] += u;
    __syncthreads();
  }
  pbase[t] = s[t] - v;
}

// one block per partition: LDS histogram over 1024 local nodes -> rowptr
// slice + cursors -> exact scatter into epack.
__global__ __launch_bounds__(256) void gnn_bin2(const uint2* __restrict__ stage,
                                                const int* __restrict__ pcur,
                                                const int* __restrict__ pbase,
                                                int* __restrict__ rowptr,
                                                unsigned* __restrict__ epack) {
  __shared__ int h[1024];
  __shared__ int ws[256];
  const int tid = threadIdx.x;
  const int p = blockIdx.x;
  const int node0 = p << 10;
  const int s0 = p * CAPP;
  const int cnt = pcur[p] - s0;
  const int gbase = pbase[p];
#pragma unroll
  for (int i = 0; i < 4; ++i) h[i * 256 + tid] = 0;
  __syncthreads();
  for (int r = tid; r < cnt; r += 256)
    atomicAdd(&h[(int)stage[s0 + r].y - node0], 1);
  __syncthreads();
  int a0 = h[tid * 4 + 0], a1 = h[tid * 4 + 1], a2 = h[tid * 4 + 2], a3 = h[tid * 4 + 3];
  int s1 = a0 + a1, s2 = s1 + a2, s3 = s2 + a3;
  ws[tid] = s3;
  __syncthreads();
  for (int o = 1; o < 256; o <<= 1) {
    int u = (tid >= o) ? ws[tid - o] : 0;
    __syncthreads();
    ws[tid] += u;
    __syncthreads();
  }
  int eb = gbase + (tid ? ws[tid - 1] : 0);
  int4 rp;
  rp.x = eb; rp.y = eb + a0; rp.z = eb + s1; rp.w = eb + s2;
  *(int4*)(rowptr + node0 + tid * 4) = rp;
  h[tid * 4 + 0] = rp.x; h[tid * 4 + 1] = rp.y; h[tid * 4 + 2] = rp.z; h[tid * 4 + 3] = rp.w;
  if (p == 127 && tid == 255) rowptr[NODES] = EDGES;
  __syncthreads();
  for (int r = tid; r < cnt; r += 256) {
    uint2 q = stage[s0 + r];
    int pos = atomicAdd(&h[(int)q.y - node0], 1);
    epack[pos] = q.x;
  }
}

// ============================================================================
// bf16 helpers
// ============================================================================
__device__ __forceinline__ unsigned gnn_pack2bf(float a, float b) {
  union { float f; unsigned u; } x, y; x.f = a; y.f = b;
  unsigned ua = (x.u + 0x7FFFu + ((x.u >> 16) & 1u)) >> 16;
  unsigned ub = (y.u + 0x7FFFu + ((y.u >> 16) & 1u)) >> 16;
  return ua | (ub << 16);
}

__device__ __forceinline__ u16 gnn_f2bf(float a) {
  union { float f; unsigned u; } x; x.f = a;
  return (u16)((x.u + 0x7FFFu + ((x.u >> 16) & 1u)) >> 16);
}

__device__ __forceinline__ float gnn_bf2f(u16 h) {
  union { unsigned u; float f; } x; x.u = ((unsigned)h) << 16; return x.f;
}

__device__ __forceinline__ float gnn_sig(float x)  { return 1.f / (1.f + __expf(-x)); }
__device__ __forceinline__ float gnn_tanh(float x) { return 1.f - 2.f / (1.f + __expf(2.f * x)); }

// ============================================================================
// t[i,:] = sum_{e in CSR[i]} ew_e * x[src_e,:]   (one wave per node, bf16 x)
// lane covers cols {2*lane, 2*lane+1}; one 256B coalesced row read per edge.
// 16-deep software pipeline.
// ============================================================================
__device__ __forceinline__ void gnn_agg_edge(const u16* __restrict__ X, unsigned q, int lane,
                                             float& a0, float& a1) {
  unsigned pv = *(const unsigned*)(X + (long)(q >> 15) * H + lane * 2);
  float w = (float)(q & 0x7FFFu) * (1.f / 32768.f);
  union { unsigned u; float f; } lo, hi;
  lo.u = pv << 16; hi.u = pv & 0xFFFF0000u;
  a0 = fmaf(w, lo.f, a0);
  a1 = fmaf(w, hi.f, a1);
}

__global__ __launch_bounds__(256) void gnn_agg(const u16* __restrict__ X, const int* __restrict__ rowptr,
                                               const unsigned* __restrict__ epack,
                                               u16* __restrict__ T) {
  int wave = threadIdx.x >> 6, lane = threadIdx.x & 63;
  long node = (long)blockIdx.x * 4 + wave;
  int e0 = rowptr[node], e1 = rowptr[node + 1];
  float a0 = 0.f, a1 = 0.f;
  int e = e0;
  for (; e + 16 <= e1; e += 16) {
    unsigned q[16];
#pragma unroll
    for (int j = 0; j < 16; ++j) q[j] = epack[e + j];
    unsigned p[16];
#pragma unroll
    for (int j = 0; j < 16; ++j) p[j] = *(const unsigned*)(X + (long)(q[j] >> 15) * H + lane * 2);
#pragma unroll
    for (int j = 0; j < 16; ++j) {
      float w = (float)(q[j] & 0x7FFFu) * (1.f / 32768.f);
      union { unsigned u; float f; } lo, hi;
      lo.u = p[j] << 16; hi.u = p[j] & 0xFFFF0000u;
      a0 = fmaf(w, lo.f, a0);
      a1 = fmaf(w, hi.f, a1);
    }
  }
  if (e + 8 <= e1) {
    unsigned q[8];
#pragma unroll
    for (int j = 0; j < 8; ++j) q[j] = epack[e + j];
    unsigned p[8];
#pragma unroll
    for (int j = 0; j < 8; ++j) p[j] = *(const unsigned*)(X + (long)(q[j] >> 15) * H + lane * 2);
#pragma unroll
    for (int j = 0; j < 8; ++j) {
      float w = (float)(q[j] & 0x7FFFu) * (1.f / 32768.f);
      union { unsigned u; float f; } lo, hi;
      lo.u = p[j] << 16; hi.u = p[j] & 0xFFFF0000u;
      a0 = fmaf(w, lo.f, a0);
      a1 = fmaf(w, hi.f, a1);
    }
    e += 8;
  }
  if (e + 4 <= e1) {
    unsigned q[4];
#pragma unroll
    for (int j = 0; j < 4; ++j) q[j] = epack[e + j];
#pragma unroll
    for (int j = 0; j < 4; ++j) gnn_agg_edge(X, q[j], lane, a0, a1);
    e += 4;
  }
  for (; e < e1; ++e) gnn_agg_edge(X, epack[e], lane, a0, a1);
  *(unsigned*)(T + node * H + lane * 2) = gnn_pack2bf(a0, a1);
}

// ============================================================================
// weight prep: Wc = W[l] @ wi.T  (128x384), whT = wh.T (128x384)
// ============================================================================
__global__ __launch_bounds__(384) void gnn_prep_wc(const float* __restrict__ Wl, const float* __restrict__ wi,
                                                   float* __restrict__ Wc) {
  __shared__ float wrow[128];
  int k = blockIdx.x, j = threadIdx.x;
  if (j < 128) wrow[j] = Wl[k * 128 + j];
  __syncthreads();
  float acc = 0.f;
  for (int m = 0; m < 128; ++m) acc = fmaf(wrow[m], wi[j * 128 + m], acc);
  Wc[k * 384 + j] = acc;
}

__global__ __launch_bounds__(384) void gnn_prep_whT(const float* __restrict__ wh1, const float* __restrict__ wh2,
                                                    float* __restrict__ whT) {
  int c = blockIdx.x >> 7, k = blockIdx.x & 127, j = threadIdx.x;
  const float* wh = c ? wh2 : wh1;
  whT[((long)c * 128 + k) * 384 + j] = wh[j * 128 + k];
}

// ============================================================================
// MFMA fragment plumbing
// A-frag layout (16x16x32): A[m=lane&15][k=(lane>>4)*8+j]
// B-frag layout:            B[k=(lane>>4)*8+j][n=lane&15]
// C/D layout:               col=lane&15, row=(lane>>4)*4+reg
// LDS A staging: slot(ktq,row) = ktq*64 + (row ^ (ktq&7)), 16B per slot
// ============================================================================
template<int K>
__device__ __forceinline__ void gnn_stage_bf(const u16* __restrict__ A, long row0,
                                             u16* lds, int tid) {
  constexpr int CH = K / 8;     // 16B chunks per row
#pragma unroll
  for (int it = 0; it < (64 * CH) / 256; ++it) {
    int c = it * 256 + tid;
    int row = c / CH, ktq = c % CH;
    uint4 v = *(const uint4*)(A + (row0 + row) * K + ktq * 8);
    int slot = ktq * 64 + (row ^ (ktq & 7));
    *(uint4*)(lds + slot * 8) = v;
  }
}

__device__ __forceinline__ bf16x8 gnn_afrag(const u16* lds, int rt, int ktq, int l16) {
  int slot = ktq * 64 + ((rt * 16 + l16) ^ (ktq & 7));
  return *(const bf16x8*)(lds + slot * 8);
}

__device__ __forceinline__ bf16x8 gnn_bfrag(const u16* __restrict__ pk,
                                            int ct, int kt, int KT, int lane) {
  return *(const bf16x8*)(pk + (((long)(ct * KT + kt)) * 64 + lane) * 8);
}

// pack fp32 weight into B-fragment bf16 layout
__global__ __launch_bounds__(64) void gnn_pack(const float* __restrict__ W0, const float* __restrict__ W1,
                                               int ksplit, int LD, int coff, int KT,
                                               u16* __restrict__ dst) {
  int b = blockIdx.x;
  int kt = b % KT, ct = b / KT;
  int lane = threadIdx.x;
  int col = ct * 16 + (lane & 15) + coff;
  int kb = kt * 32 + ((lane >> 4) & 3) * 8;
  u16 h[8];
#pragma unroll
  for (int j = 0; j < 8; ++j) {
    int k = kb + j;
    float v = (k < ksplit) ? W0[(long)k * LD + col] : W1[(long)(k - ksplit) * LD + col];
    h[j] = gnn_f2bf(v);
  }
  uint4 o;
  o.x = (unsigned)h[0] | ((unsigned)h[1] << 16);
  o.y = (unsigned)h[2] | ((unsigned)h[3] << 16);
  o.z = (unsigned)h[4] | ((unsigned)h[5] << 16);
  o.w = (unsigned)h[6] | ((unsigned)h[7] << 16);
  ((uint4*)dst)[(long)b * 64 + lane] = o;
}

// ============================================================================
// MFMA GEMM: C[M x N] = act(A[M x K] @ Wpk + bias), 64-row blocks, 256 thr.
// ============================================================================
template<int K, int N, int ACT, int BMODE>
__global__ __launch_bounds__(256) void gnn_mgemm(const u16* __restrict__ A,
                                                 const u16* __restrict__ pk,
                                                 const float* __restrict__ bias,
                                                 u16* __restrict__ C) {
  constexpr int KT = K / 32;
  constexpr int CT = N / 64;       // col-tiles per wave
  __shared__ u16 As[64 * K];
  const int tid = threadIdx.x;
  const int lane = tid & 63, wave = tid >> 6;
  const int quad = lane >> 4, l16 = lane & 15;
  const long row0 = (long)blockIdx.x * 64;
  gnn_stage_bf<K>(A, row0, As, tid);
  __syncthreads();

  f32x4 zero4 = {0.f, 0.f, 0.f, 0.f};
  f32x4 acc[4][CT];
#pragma unroll
  for (int rt = 0; rt < 4; ++rt)
#pragma unroll
    for (int ct = 0; ct < CT; ++ct) acc[rt][ct] = zero4;

#pragma unroll
  for (int kt = 0; kt < KT; ++kt) {
    int ktq = kt * 4 + quad;
    bf16x8 af[4];
#pragma unroll
    for (int rt = 0; rt < 4; ++rt) af[rt] = gnn_afrag(As, rt, ktq, l16);
#pragma unroll
    for (int ct = 0; ct < CT; ++ct) {
      bf16x8 bf = gnn_bfrag(pk, wave * CT + ct, kt, KT, lane);
#pragma unroll
      for (int rt = 0; rt < 4; ++rt)
        acc[rt][ct] = __builtin_amdgcn_mfma_f32_16x16x32_bf16(af[rt], bf, acc[rt][ct], 0, 0, 0);
    }
  }

  const float* bp = (BMODE == 0) ? bias : (bias + (row0 >> 12) * N);
#pragma unroll
  for (int ct = 0; ct < CT; ++ct) {
    int col = (wave * CT + ct) * 16 + l16;
    float bv = bp[col];
#pragma unroll
    for (int rt = 0; rt < 4; ++rt) {
      long row = row0 + rt * 16 + quad * 4;
#pragma unroll
      for (int r = 0; r < 4; ++r) {
        float v = acc[rt][ct][r] + bv;
        if (ACT) v = fmaxf(v, 0.f);
        C[(row + r) * N + col] = gnn_f2bf(v);
      }
    }
  }
}

// ============================================================================
// MFMA GRU: Y = GRUCell(m = T@Wc, h = X), all node tensors bf16.
// ============================================================================
template<int RELU>
__global__ __launch_bounds__(256) void gnn_mgru(const u16* __restrict__ T, const u16* __restrict__ X,
                                                const u16* __restrict__ pkRZ,
                                                const u16* __restrict__ pkAI,
                                                const u16* __restrict__ pkAH,
                                                const float* __restrict__ bi, const float* __restrict__ bh,
                                                u16* __restrict__ Y) {
  __shared__ u16 Ts[64 * 128];
  __shared__ u16 Xs[64 * 128];
  const int tid = threadIdx.x;
  const int lane = tid & 63, wave = tid >> 6;
  const int quad = lane >> 4, l16 = lane & 15;
  const long row0 = (long)blockIdx.x * 64;
  gnn_stage_bf<128>(T, row0, Ts, tid);
  gnn_stage_bf<128>(X, row0, Xs, tid);
  __syncthreads();

  f32x4 zero4 = {0.f, 0.f, 0.f, 0.f};
  f32x4 ai[4][2], ah[4][2], rr[4][2];
#pragma unroll
  for (int rt = 0; rt < 4; ++rt)
#pragma unroll
    for (int c = 0; c < 2; ++c) { ai[rt][c] = zero4; ah[rt][c] = zero4; rr[rt][c] = zero4; }

  // fused K-loop: ai (T), ah (X), r (T,X)
#pragma unroll
  for (int kt = 0; kt < 4; ++kt) {
    int ktq = kt * 4 + quad;
    bf16x8 tf[4], xf[4];
#pragma unroll
    for (int rt = 0; rt < 4; ++rt) { tf[rt] = gnn_afrag(Ts, rt, ktq, l16); xf[rt] = gnn_afrag(Xs, rt, ktq, l16); }
#pragma unroll
    for (int c = 0; c < 2; ++c) {
      int ct = wave * 2 + c;
      bf16x8 bAI = gnn_bfrag(pkAI, ct, kt, 4, lane);
      bf16x8 bAH = gnn_bfrag(pkAH, ct, kt, 4, lane);
      bf16x8 bRT = gnn_bfrag(pkRZ, ct, kt,     8, lane);
      bf16x8 bRX = gnn_bfrag(pkRZ, ct, kt + 4, 8, lane);
#pragma unroll
      for (int rt = 0; rt < 4; ++rt) {
        ai[rt][c] = __builtin_amdgcn_mfma_f32_16x16x32_bf16(tf[rt], bAI, ai[rt][c], 0, 0, 0);
        ah[rt][c] = __builtin_amdgcn_mfma_f32_16x16x32_bf16(xf[rt], bAH, ah[rt][c], 0, 0, 0);
        rr[rt][c] = __builtin_amdgcn_mfma_f32_16x16x32_bf16(tf[rt], bRT, rr[rt][c], 0, 0, 0);
        rr[rt][c] = __builtin_amdgcn_mfma_f32_16x16x32_bf16(xf[rt], bRX, rr[rt][c], 0, 0, 0);
      }
    }
  }

  // biases for this lane's two gate columns
  float brz[2], bzz[2], bin_[2], bhn[2];
#pragma unroll
  for (int c = 0; c < 2; ++c) {
    int col = (wave * 2 + c) * 16 + l16;
    brz[c]  = bi[col] + bh[col];
    bzz[c]  = bi[128 + col] + bh[128 + col];
    bin_[c] = bi[256 + col];
    bhn[c]  = bh[256 + col];
  }

  // n = tanh(ai + bi_n + r*(ah + bh_n))   (n overwrites ai)
#pragma unroll
  for (int rt = 0; rt < 4; ++rt)
#pragma unroll
    for (int c = 0; c < 2; ++c)
#pragma unroll
      for (int r = 0; r < 4; ++r) {
        float rv = gnn_sig(rr[rt][c][r] + brz[c]);
        ai[rt][c][r] = gnn_tanh(ai[rt][c][r] + bin_[c] + rv * (ah[rt][c][r] + bhn[c]));
      }

  // z gate
  f32x4 zz[4][2];
#pragma unroll
  for (int rt = 0; rt < 4; ++rt)
#pragma unroll
    for (int c = 0; c < 2; ++c) zz[rt][c] = zero4;
#pragma unroll
  for (int kt = 0; kt < 4; ++kt) {
    int ktq = kt * 4 + quad;
    bf16x8 tf[4], xf[4];
#pragma unroll
    for (int rt = 0; rt < 4; ++rt) { tf[rt] = gnn_afrag(Ts, rt, ktq, l16); xf[rt] = gnn_afrag(Xs, rt, ktq, l16); }
#pragma unroll
    for (int c = 0; c < 2; ++c) {
      int ct = wave * 2 + c;
      bf16x8 bZT = gnn_bfrag(pkRZ, 8 + ct, kt,     8, lane);
      bf16x8 bZX = gnn_bfrag(pkRZ, 8 + ct, kt + 4, 8, lane);
#pragma unroll
      for (int rt = 0; rt < 4; ++rt) {
        zz[rt][c] = __builtin_amdgcn_mfma_f32_16x16x32_bf16(tf[rt], bZT, zz[rt][c], 0, 0, 0);
        zz[rt][c] = __builtin_amdgcn_mfma_f32_16x16x32_bf16(xf[rt], bZX, zz[rt][c], 0, 0, 0);
      }
    }
  }

  // combine + store (h read bf16 from global X)
#pragma unroll
  for (int rt = 0; rt < 4; ++rt)
#pragma unroll
    for (int c = 0; c < 2; ++c) {
      int col = (wave * 2 + c) * 16 + l16;
      long rowb = row0 + rt * 16 + quad * 4;
#pragma unroll
      for (int r = 0; r < 4; ++r) {
        float z = gnn_sig(zz[rt][c][r] + bzz[c]);
        float h = gnn_bf2f(X[(rowb + r) * H + col]);
        float v = (1.f - z) * ai[rt][c][r] + z * h;
        if (RELU) v = fmaxf(v, 0.f);
        Y[(rowb + r) * H + col] = gnn_f2bf(v);
      }
    }
}

// ============================================================================
// fp32-input GEMM (emb1, K=16 only), bf16 output
// ============================================================================
#define GFMA(i, av) \
  acc[(i)*4+0] = fmaf((av), wv.x, acc[(i)*4+0]); \
  acc[(i)*4+1] = fmaf((av), wv.y, acc[(i)*4+1]); \
  acc[(i)*4+2] = fmaf((av), wv.z, acc[(i)*4+2]); \
  acc[(i)*4+3] = fmaf((av), wv.w, acc[(i)*4+3]);

__global__ __launch_bounds__(256) void gnn_gemm16(const float* __restrict__ A, const float* __restrict__ W,
                                                  const float* __restrict__ bias, u16* __restrict__ C,
                                                  int OUT) {
  const int K = 16;
  __shared__ float AsT[16][68];   // [k][row]
  __shared__ float Ws[16][68];    // [k][col]
  const int tid = threadIdx.x;
  const int tx = tid & 15, ty = tid >> 4;
  const long row0 = (long)blockIdx.y * 64;
  const int col0 = blockIdx.x * 64;
  const int lr  = tid >> 2;
  const int lk4 = (tid & 3) * 4;
  const int wk  = tid >> 4;
  const int wj4 = (tid & 15) * 4;
  float acc[16];
#pragma unroll
  for (int i = 0; i < 16; ++i) acc[i] = 0.f;

  {
    float4 a = *(const float4*)(A + (row0 + lr) * K + lk4);
    float4 w = *(const float4*)(W + (long)wk * OUT + col0 + wj4);
    AsT[lk4 + 0][lr] = a.x; AsT[lk4 + 1][lr] = a.y; AsT[lk4 + 2][lr] = a.z; AsT[lk4 + 3][lr] = a.w;
    *(float4*)(&Ws[wk][wj4]) = w;
    __syncthreads();
#pragma unroll
    for (int k = 0; k < 16; ++k) {
      float4 av = *(const float4*)(&AsT[k][ty * 4]);
      float4 wv = *(const float4*)(&Ws[k][tx * 4]);
      GFMA(0, av.x) GFMA(1, av.y) GFMA(2, av.z) GFMA(3, av.w)
    }
  }
#pragma unroll
  for (int i = 0; i < 4; ++i) {
    long row = row0 + ty * 4 + i;
    int j = col0 + tx * 4;
    float4 o;
    o.x = fmaxf(acc[i * 4 + 0] + bias[j + 0], 0.f);
    o.y = fmaxf(acc[i * 4 + 1] + bias[j + 1], 0.f);
    o.z = fmaxf(acc[i * 4 + 2] + bias[j + 2], 0.f);
    o.w = fmaxf(acc[i * 4 + 3] + bias[j + 3], 0.f);
    uint2 st;
    st.x = gnn_pack2bf(o.x, o.y);
    st.y = gnn_pack2bf(o.z, o.w);
    *(uint2*)(C + row * OUT + j) = st;
  }
}
#undef GFMA

// ============================================================================
// head: pool, per-graph bias, item-value init, final bound reduction
// ============================================================================
__global__ __launch_bounds__(128) void gnn_pool(const u16* __restrict__ X3, float* __restrict__ ge) {
  int b = blockIdx.x >> 3, chunk = blockIdx.x & 7, t = threadIdx.x;
  long base = ((long)b * PP + chunk * 512) * H;
  float acc = 0.f;
  for (int p = 0; p < 512; ++p) acc += gnn_bf2f(X3[base + (long)p * H + t]);
  atomicAdd(&ge[b * H + t], acc);
}

__global__ __launch_bounds__(256) void gnn_gbias(const float* __restrict__ ge, const float* __restrict__ Wl1b,
                                                 const float* __restrict__ bl1, float* __restrict__ gb) {
  __shared__ float g[128];
  int b = blockIdx.x, t = threadIdx.x;
  if (t < 128) g[t] = ge[b * H + t] * (1.f / 4096.f);
  __syncthreads();
  float acc = bl1[t];
  for (int k = 0; k < 128; ++k) acc = fmaf(g[k], Wl1b[k * 256 + t], acc);
  gb[b * 256 + t] = acc;
}

__global__ __launch_bounds__(256) void gnn_item(const float* __restrict__ iv, const int* __restrict__ vvs,
                                                float* __restrict__ out) {
  __shared__ float s[256];
  int b = blockIdx.x, t = threadIdx.x;
  float v = iv[b * 256 + t] * (float)vvs[(long)b * PP + t];   // sol[b,0,n]
  s[t] = v; __syncthreads();
  for (int off = 128; off > 0; off >>= 1) {
    if (t < off) s[t] += s[t + off];
    __syncthreads();
  }
  if (t == 0) out[b] = s[0];
}

__global__ __launch_bounds__(256) void gnn_bound(const u16* __restrict__ U2, const float* __restrict__ wl3,
                                                 const float* __restrict__ bl3, const int* __restrict__ vvs,
                                                 float* __restrict__ out) {
  int tid = threadIdx.x;
  int wave = tid >> 6, lane = tid & 63;
  int b = blockIdx.x >> 6;
  long node0 = (long)blockIdx.x * 64 + wave * 16;
  float w0 = wl3[lane * 2], w1 = wl3[lane * 2 + 1];
  float bl = bl3[0];
  float acc = 0.f;
  for (int i = 0; i < 16; ++i) {
    long node = node0 + i;
    unsigned pv = *(const unsigned*)(U2 + node * H + lane * 2);
    union { unsigned u; float f; } lo, hi;
    lo.u = pv << 16; hi.u = pv & 0xFFFF0000u;
    float p = lo.f * w0 + hi.f * w1;
#pragma unroll
    for (int off = 32; off > 0; off >>= 1) p += __shfl_down(p, off);
    if (lane == 0) {
      int pp = (int)(node & (PP - 1));
      int m = pp >> 8, n = pp & 255;
      if (m != 0) {
        float dx = (float)(vvs[((long)b << 12) + n] - vvs[((long)b << 12) + pp]);
        acc += (p + bl) * dx;
      }
    }
  }
  __shared__ float s[4];
  if (lane == 0) s[wave] = acc;
  __syncthreads();
  if (tid == 0) atomicAdd(&out[b], s[0] + s[1] + s[2] + s[3]);
}

// ============================================================================
extern "C" void kernel_launch(void* const* d_in, const int* in_sizes, int n_in,
                              void* d_out, int out_size, void* d_ws, size_t ws_size,
                              hipStream_t stream) {
  const float* G      = (const float*)d_in[0];
  const int*   ei     = (const int*)d_in[1];
  const int*   esrc   = ei;
  const int*   edst   = ei + EDGES;
  const float* ew     = (const float*)d_in[2];
  const int*   vvs    = (const int*)d_in[4];
  const float* iv     = (const float*)d_in[5];
  const float* W_emb1 = (const float*)d_in[6];
  const float* b_emb1 = (const float*)d_in[7];
  const float* W_emb2 = (const float*)d_in[8];
  const float* b_emb2 = (const float*)d_in[9];
  const float* c1_W   = (const float*)d_in[10];
  const float* c1_wi  = (const float*)d_in[11];
  const float* c1_wh  = (const float*)d_in[12];
  const float* c1_bi  = (const float*)d_in[13];
  const float* c1_bh  = (const float*)d_in[14];
  const float* c2_W   = (const float*)d_in[15];
  const float* c2_wi  = (const float*)d_in[16];
  const float* c2_wh  = (const float*)d_in[17];
  const float* c2_bi  = (const float*)d_in[18];
  const float* c2_bh  = (const float*)d_in[19];
  const float* W_g1   = (const float*)d_in[20];
  const float* b_g1   = (const float*)d_in[21];
  const float* W_g2   = (const float*)d_in[22];
  const float* b_g2   = (const float*)d_in[23];
  const float* W_l1   = (const float*)d_in[24];
  const float* b_l1   = (const float*)d_in[25];
  const float* W_l2   = (const float*)d_in[26];
  const float* b_l2   = (const float*)d_in[27];
  const float* W_l3   = (const float*)d_in[28];
  const float* b_l3   = (const float*)d_in[29];
  float* out = (float*)d_out;
  (void)in_sizes; (void)n_in; (void)out_size; (void)ws_size;

  // ---- workspace carve (~198 MiB) ----
  char* wsb = (char*)d_ws;
  size_t off = 0;
  auto carve = [&](size_t bytes) -> char* {
    char* p = wsb + off;
    off += (bytes + 255) & ~(size_t)255;
    return p;
  };
  u16*   xa     = (u16*)carve(sizeof(u16) * (size_t)NODES * H);
  u16*   xc     = (u16*)carve(sizeof(u16) * (size_t)NODES * H);
  u16*   tb     = (u16*)carve(sizeof(u16) * (size_t)NODES * H);
  u16*   u1b    = (u16*)carve(sizeof(u16) * (size_t)NODES * 256);
  float* Wc     = (float*)carve(sizeof(float) * 4 * H * 384);
  float* whT    = (float*)carve(sizeof(float) * 2 * H * 384);
  u16*   pk     = (u16*)carve(sizeof(u16) * 507904);
  int*   rowptr = (int*)carve(sizeof(int) * (NODES + 1));
  int*   pcur   = (int*)carve(sizeof(int) * 128);        // bin1 partition cursors
  int*   pbase  = (int*)carve(sizeof(int) * 128);        // partition epack bases
  uint2* stage  = (uint2*)carve(sizeof(uint2) * (size_t)128 * CAPP);  // ~18.9 MB
  unsigned* epack = (unsigned*)carve(sizeof(unsigned) * EDGES);
  float* ge     = (float*)carve(sizeof(float) * NB * H);
  float* gb     = (float*)carve(sizeof(float) * NB * 256);

  // packed-weight offsets (halves)
  const long RZ = 65536, AI = 16384, AH = 16384, LYR = RZ + AI + AH;  // 98304/layer
  u16* pkRZ[4]; u16* pkAI[4]; u16* pkAH[4];
  for (int l = 0; l < 4; ++l) {
    pkRZ[l] = pk + l * LYR;
    pkAI[l] = pk + l * LYR + RZ;
    pkAH[l] = pk + l * LYR + RZ + AI;
  }
  u16* pe2 = pk + 4 * LYR;
  u16* pg1 = pe2 + 16384;
  u16* pg2 = pg1 + 16384;
  u16* pl1 = pg2 + 16384;
  u16* pl2 = pl1 + 32768;

  // ---- CSR build: pinit -> bin1 (slab stage) -> pscan -> bin2 (hist+scan+scatter)
  hipMemsetAsync(ge, 0, sizeof(float) * NB * H, stream);
  gnn_pinit<<<1, 128, 0, stream>>>(pcur);
  gnn_bin1<<<B1_BLOCKS, 256, 0, stream>>>(esrc, edst, ew, pcur, stage);
  gnn_pscan<<<1, 128, 0, stream>>>(pcur, pbase);
  gnn_bin2<<<128, 256, 0, stream>>>(stage, pcur, pbase, rowptr, epack);

  // ---- weight prep: Wc[l] = W[l] @ wi.T ; whT = wh.T ----
  gnn_prep_wc<<<128, 384, 0, stream>>>(c1_W,             c1_wi, Wc + 0 * 128 * 384);
  gnn_prep_wc<<<128, 384, 0, stream>>>(c1_W + 128 * 128, c1_wi, Wc + 1 * 128 * 384);
  gnn_prep_wc<<<128, 384, 0, stream>>>(c2_W,             c2_wi, Wc + 2 * 128 * 384);
  gnn_prep_wc<<<128, 384, 0, stream>>>(c2_W + 128 * 128, c2_wi, Wc + 3 * 128 * 384);
  gnn_prep_whT<<<256, 384, 0, stream>>>(c1_wh, c2_wh, whT);

  // ---- pack weights to MFMA B-frag bf16 ----
  for (int l = 0; l < 4; ++l) {
    const float* Wcl = Wc + (long)l * 128 * 384;
    const float* whl = whT + (long)(l >> 1) * 128 * 384;
    gnn_pack<<<16 * 8, 64, 0, stream>>>(Wcl, whl, 128, 384, 0,   8, pkRZ[l]);   // rz: K=256, N=256
    gnn_pack<<<8 * 4, 64, 0, stream>>>(Wcl, Wcl, 128, 384, 256, 4, pkAI[l]);    // ai: K=128, N=128
    gnn_pack<<<8 * 4, 64, 0, stream>>>(whl, whl, 128, 384, 256, 4, pkAH[l]);    // ah
  }
  gnn_pack<<<8 * 4, 64, 0, stream>>>(W_emb2, W_emb2, 128, 128, 0, 4, pe2);
  gnn_pack<<<8 * 4, 64, 0, stream>>>(W_g1,  W_g1,  128, 128, 0, 4, pg1);
  gnn_pack<<<8 * 4, 64, 0, stream>>>(W_g2,  W_g2,  128, 128, 0, 4, pg2);
  gnn_pack<<<16 * 4, 64, 0, stream>>>(W_l1, W_l1,  128, 256, 0, 4, pl1);        // x-part only (K=128,N=256)
  gnn_pack<<<8 * 8, 64, 0, stream>>>(W_l2,  W_l2,  256, 128, 0, 8, pl2);        // K=256,N=128

  // ---- embeddings: G -> xa -> xc ----
  gnn_gemm16<<<dim3(2, NODES / 64), 256, 0, stream>>>(G, W_emb1, b_emb1, xa, 128);
  gnn_mgemm<128, 128, 1, 0><<<NODES / 64, 256, 0, stream>>>(xa, pe2, b_emb2, xc);

  // ---- conv1 (x in xc) ----
  gnn_agg<<<NODES / 4, 256, 0, stream>>>(xc, rowptr, epack, tb);
  gnn_mgru<0><<<NODES / 64, 256, 0, stream>>>(tb, xc, pkRZ[0], pkAI[0], pkAH[0], c1_bi, c1_bh, xa);
  gnn_agg<<<NODES / 4, 256, 0, stream>>>(xa, rowptr, epack, tb);
  gnn_mgru<1><<<NODES / 64, 256, 0, stream>>>(tb, xa, pkRZ[1], pkAI[1], pkAH[1], c1_bi, c1_bh, xc);

  // ---- conv2 (x in xc) ----
  gnn_agg<<<NODES / 4, 256, 0, stream>>>(xc, rowptr, epack, tb);
  gnn_mgru<0><<<NODES / 64, 256, 0, stream>>>(tb, xc, pkRZ[2], pkAI[2], pkAH[2], c2_bi, c2_bh, xa);
  gnn_agg<<<NODES / 4, 256, 0, stream>>>(xa, rowptr, epack, tb);
  gnn_mgru<1><<<NODES / 64, 256, 0, stream>>>(tb, xa, pkRZ[3], pkAI[3], pkAH[3], c2_bi, c2_bh, xc);

  // ---- head GEMMs: xc -> xa -> tb (x3) ----
  gnn_mgemm<128, 128, 1, 0><<<NODES / 64, 256, 0, stream>>>(xc, pg1, b_g1, xa);
  gnn_mgemm<128, 128, 0, 0><<<NODES / 64, 256, 0, stream>>>(xa, pg2, b_g2, tb);

  // ---- pool + per-graph bias (folds ge @ W_l1[128:] + b_l1) ----
  gnn_pool<<<NB * 8, 128, 0, stream>>>(tb, ge);
  gnn_gbias<<<NB, 256, 0, stream>>>(ge, W_l1 + 128 * 256, b_l1, gb);

  // ---- MLP: l1 (graph-bias), l2, l3+reduction ----
  gnn_mgemm<128, 256, 1, 1><<<NODES / 64, 256, 0, stream>>>(tb, pl1, gb, u1b);
  gnn_mgemm<256, 128, 1, 0><<<NODES / 64, 256, 0, stream>>>(u1b, pl2, b_l2, xa);  // u2 in xa
  gnn_item<<<NB, 256, 0, stream>>>(iv, vvs, out);
  gnn_bound<<<NODES / 64, 256, 0, stream>>>(xa, W_l3, b_l3, vvs, out);
}